// Round 5
// baseline (25366.232 us; speedup 1.0000x reference)
//
#include <hip/hip_runtime.h>

typedef __attribute__((ext_vector_type(8))) short short8;
typedef __attribute__((ext_vector_type(4))) float floatx4;

// ---------- helpers ----------
__device__ __forceinline__ unsigned short f2bf(float f) {
  unsigned int u = __float_as_uint(f);
  unsigned int lsb = (u >> 16) & 1u;
  u += 0x7fffu + lsb;  // round-to-nearest-even
  return (unsigned short)(u >> 16);
}
__device__ __forceinline__ float bf2f(unsigned short u) {
  unsigned int x = ((unsigned int)u) << 16;
  return __uint_as_float(x);
}
__device__ __forceinline__ float sigm(float x) { return 1.f / (1.f + __expf(-x)); }
__device__ __forceinline__ float tanh_fast(float x) { return 2.f / (1.f + __expf(-2.f * x)) - 1.f; }
__device__ __forceinline__ floatx4 mfma16(short8 a, short8 b, floatx4 c) {
  return __builtin_amdgcn_mfma_f32_16x16x32_bf16(a, b, c, 0, 0, 0);
}

// ---------- prep ----------
__global__ void wc_kernel(const float* __restrict__ Wih0, const float* __restrict__ inW,
                          const float* __restrict__ inb, const float* __restrict__ bih0,
                          const float* __restrict__ bhh0, unsigned short* __restrict__ Wc,
                          float* __restrict__ bc) {
  const int n = blockIdx.x;   // 0..1023
  const int k = threadIdx.x;  // 0..127
  float a = 0.f;
  for (int j = 0; j < 256; ++j) a += Wih0[n * 256 + j] * inW[j * 128 + k];
  Wc[n * 128 + k] = f2bf(a);
  if (k == 0) {
    float bsum = bih0[n] + bhh0[n];
    for (int j = 0; j < 256; ++j) bsum += Wih0[n * 256 + j] * inb[j];
    bc[n] = bsum;
  }
}

__global__ void cvt_kernel(unsigned short* __restrict__ dst, const float* __restrict__ src, int n) {
  int i = blockIdx.x * 256 + threadIdx.x;
  if (i < n) dst[i] = f2bf(src[i]);
}

__global__ void addb_kernel(float* __restrict__ b1, const float* __restrict__ xa,
                            const float* __restrict__ ya, int n) {
  int i = blockIdx.x * 256 + threadIdx.x;
  if (i < n) b1[i] = xa[i] + ya[i];
}

// ---------- BatchNorm + spatial attention ----------
__global__ __launch_bounds__(128) void bnsa_kernel(
    const float* __restrict__ x, const float* __restrict__ gamma,
    const float* __restrict__ beta, const float* __restrict__ mean,
    const float* __restrict__ var, const float* __restrict__ saW,
    const float* __restrict__ sab, unsigned short* __restrict__ xs, int rowsPerWg) {
  __shared__ unsigned short saT[128 * 128];  // bf16 [k][j] = saW[j][k]
  __shared__ float xbuf[128];
  __shared__ float ebuf[128];
  const int j = threadIdx.x;
  for (int k = 0; k < 128; ++k) saT[k * 128 + j] = f2bf(saW[j * 128 + k]);
  const float g = gamma[j], bt = beta[j], mn = mean[j];
  const float istd = rsqrtf(var[j] + 1e-5f);
  const float sb = sab[j];
  __syncthreads();
  const long row0 = (long)blockIdx.x * rowsPerWg;
  for (int it = 0; it < rowsPerWg; ++it) {
    const long row = row0 + it;
    const float xv = x[row * 128 + j];
    const float xb = (xv - mn) * istd * g + bt;
    xbuf[j] = xb;
    __syncthreads();
    float s = sb;
#pragma unroll 8
    for (int k = 0; k < 128; ++k) s += xbuf[k] * bf2f(saT[k * 128 + j]);
    const float e = __expf(sigm(s));
    ebuf[j] = e;
    __syncthreads();
    float sum = 0.f;
#pragma unroll 8
    for (int k = 0; k < 128; ++k) sum += ebuf[k];
    xs[row * 128 + j] = f2bf(xb * (e / sum));
    __syncthreads();
  }
}

// ---------- N-split persistent kernel with MALL-atomic exchange ----------
// 128 wgs = 16 batch-groups x 8 slices; 512 thr (8 waves).
// Wave wv: gate g=wv&3, hidden tile ht=wv>>2 -> gate row ng = g*256 + slice*32 + ht*16 + lm.
// Weights VGPR/AGPR-resident (loaded once). Cross-wg h exchange: packed 8B agent-scope
// relaxed atomics (MALL-coherent, no L2 flush); data->flag ordering via per-wave s_waitcnt(0);
// 2 sub-flags (one per publishing wave) packed in one u64 so readers poll a single load.
__global__ __launch_bounds__(512, 2) void persist_kernel(
    const unsigned short* __restrict__ xs,  // [B,T,128] bf16
    const unsigned short* __restrict__ Wc, const float* __restrict__ bc,
    const unsigned short* __restrict__ Whh0,
    const unsigned short* __restrict__ Wih1, const float* __restrict__ b1,
    const unsigned short* __restrict__ Whh1,
    const unsigned short* __restrict__ tahWg, const float* __restrict__ tahb,
    const unsigned short* __restrict__ taWg, const float* __restrict__ tab,
    const float* __restrict__ outW,
    unsigned long long* __restrict__ ex,      // [2 layers][2 parity][16 groups][1024 qwords]
    unsigned long long* __restrict__ flagsQ,  // [2][2][16][8 slices] (2 sub-dwords each)
    float* __restrict__ out) {
  __shared__ unsigned short tahWs[128 * 264];  // [f][k], k<256
  __shared__ unsigned short taWs[128 * 136];   // [f][j], j<128
  __shared__ unsigned short h0buf[16 * 264];
  __shared__ unsigned short h1buf[16 * 264];
  __shared__ float gatebuf[8 * 16 * 20];       // stride 20 floats: 2-way bank alias (free)
  __shared__ unsigned short totB[16 * 136];

  const int tid = threadIdx.x;
  const int wv = tid >> 6, lane = tid & 63;
  const int lm = lane & 15, q = lane >> 4;
  const int slice = blockIdx.x >> 4, group = blockIdx.x & 15;
  const int g = wv & 3, ht = wv >> 2;
  const int b0 = group * 16;
  const int hcol = slice * 32 + ht * 16 + lm;
  const int ng = g * 256 + hcol;
  const int fcol = wv * 16 + lm;

  for (int i = tid; i < 128 * 256; i += 512) tahWs[(i >> 8) * 264 + (i & 255)] = tahWg[i];
  for (int i = tid; i < 128 * 128; i += 512) taWs[(i >> 7) * 136 + (i & 127)] = taWg[i];
  for (int i = tid; i < 16 * 264; i += 512) { h0buf[i] = 0; h1buf[i] = 0; }

  // register-resident weight B-frags (loaded once)
  short8 Wcf[4], W0f[8], W1if[8], W1hf[8];
#pragma unroll
  for (int kt = 0; kt < 4; ++kt) Wcf[kt] = *(const short8*)&Wc[(size_t)ng * 128 + kt * 32 + q * 8];
#pragma unroll
  for (int kt = 0; kt < 8; ++kt) {
    W0f[kt] = *(const short8*)&Whh0[(size_t)ng * 256 + kt * 32 + q * 8];
    W1if[kt] = *(const short8*)&Wih1[(size_t)ng * 256 + kt * 32 + q * 8];
    W1hf[kt] = *(const short8*)&Whh1[(size_t)ng * 256 + kt * 32 + q * 8];
  }
  const float bcv = bc[ng], b1v = b1[ng];
  const float tahbv = tahb[fcol], tabv = tab[fcol], outWv = outW[fcol];

  floatx4 cst0 = (floatx4){0.f, 0.f, 0.f, 0.f};
  floatx4 cst1 = (floatx4){0.f, 0.f, 0.f, 0.f};
  float num[4] = {0.f, 0.f, 0.f, 0.f}, den[4] = {0.f, 0.f, 0.f, 0.f};

  const unsigned short* xrow = xs + (size_t)(b0 + lm) * 65536 + q * 8;
  short8 axf[4], axn[4];
#pragma unroll
  for (int kt = 0; kt < 4; ++kt) axf[kt] = *(const short8*)(xrow + kt * 32);

  // reader assignment: thread tid handles qwords 2*tid, 2*tid+1 -> col=tid>>1,
  // m-quads {2*(tid&1), 2*(tid&1)+1}; source slice = tid>>6 = wv (wave-uniform flag poll).
  const int rcol = tid >> 1;
  const int rq = (tid & 1) * 2;
  __syncthreads();

  for (int t = 0; t < 512; ++t) {
    const int p = t & 1;
    const size_t gbase0 = ((size_t)(0 * 2 + p) * 16 + group) * 1024;  // layer0 qword base
    const size_t gbase1 = ((size_t)(2 + p) * 16 + group) * 1024;      // layer1 qword base
    const int fi0 = ((0 * 2 + p) * 16 + group) * 8;
    const int fi1 = ((2 + p) * 16 + group) * 8;

    // ---- phase A: gates0 = xs_t @ Wc^T + h0 @ Whh0^T + bc ----
    {
      floatx4 aW = (floatx4){0.f, 0.f, 0.f, 0.f};
      floatx4 aH = (floatx4){bcv, bcv, bcv, bcv};
#pragma unroll
      for (int kt = 0; kt < 4; ++kt) aW = mfma16(axf[kt], Wcf[kt], aW);
#pragma unroll
      for (int kt = 0; kt < 8; ++kt) {
        const short8 a = *(const short8*)&h0buf[lm * 264 + kt * 32 + q * 8];
        aH = mfma16(a, W0f[kt], aH);
      }
      const floatx4 acc = aW + aH;
#pragma unroll
      for (int r = 0; r < 4; ++r) gatebuf[(wv * 16 + q * 4 + r) * 20 + lm] = acc[r];
    }
    {  // prefetch next xs frags
      const size_t tn = (t < 511) ? t + 1 : t;
#pragma unroll
      for (int kt = 0; kt < 4; ++kt) axn[kt] = *(const short8*)(xrow + tn * 128 + kt * 32);
    }
    __syncthreads();  // B1: gatebuf complete

    // ---- sync0: cell0 + publish (waves g==0), all spin+read+scatter ----
    if (g == 0) {
      unsigned long long pk = 0;
#pragma unroll
      for (int r = 0; r < 4; ++r) {
        const int m = q * 4 + r;
        const float iv = gatebuf[((ht * 4 + 0) * 16 + m) * 20 + lm];
        const float fv = gatebuf[((ht * 4 + 1) * 16 + m) * 20 + lm];
        const float gv = gatebuf[((ht * 4 + 2) * 16 + m) * 20 + lm];
        const float ov = gatebuf[((ht * 4 + 3) * 16 + m) * 20 + lm];
        const float cn = sigm(fv) * cst0[r] + sigm(iv) * tanh_fast(gv);
        cst0[r] = cn;
        pk |= (unsigned long long)f2bf(sigm(ov) * tanh_fast(cn)) << (16 * r);
      }
      __hip_atomic_store(&ex[gbase0 + (size_t)hcol * 4 + q], pk, __ATOMIC_RELAXED,
                         __HIP_MEMORY_SCOPE_AGENT);
      __asm__ __volatile__("" ::: "memory");
      __builtin_amdgcn_s_waitcnt(0);  // this wave's data stores acked at coherence point
      __asm__ __volatile__("" ::: "memory");
      if (lane == 0)
        __hip_atomic_store(&((unsigned int*)flagsQ)[(fi0 + slice) * 2 + ht], (unsigned)(t + 1),
                           __ATOMIC_RELAXED, __HIP_MEMORY_SCOPE_AGENT);
    }
    {
      const unsigned long long* fq = &flagsQ[fi0 + wv];
      unsigned long long fvq;
      do {
        fvq = __hip_atomic_load(fq, __ATOMIC_ACQUIRE, __HIP_MEMORY_SCOPE_AGENT);
      } while ((int)(fvq & 0xffffffffu) < t + 1 || (int)(fvq >> 32) < t + 1);
      const unsigned long long v0 =
          __hip_atomic_load(&ex[gbase0 + 2 * tid], __ATOMIC_RELAXED, __HIP_MEMORY_SCOPE_AGENT);
      const unsigned long long v1 =
          __hip_atomic_load(&ex[gbase0 + 2 * tid + 1], __ATOMIC_RELAXED, __HIP_MEMORY_SCOPE_AGENT);
#pragma unroll
      for (int r = 0; r < 4; ++r) {
        h0buf[(rq * 4 + r) * 264 + rcol] = (unsigned short)(v0 >> (16 * r));
        h0buf[((rq + 1) * 4 + r) * 264 + rcol] = (unsigned short)(v1 >> (16 * r));
      }
    }
    __syncthreads();  // B2: h0buf ready

    // ---- phase D: gates1 = h0_t @ Wih1^T + h1 @ Whh1^T + b1 ----
    {
      floatx4 aI = (floatx4){b1v, b1v, b1v, b1v};
      floatx4 aH = (floatx4){0.f, 0.f, 0.f, 0.f};
#pragma unroll
      for (int kt = 0; kt < 8; ++kt) {
        const short8 a = *(const short8*)&h0buf[lm * 264 + kt * 32 + q * 8];
        aI = mfma16(a, W1if[kt], aI);
      }
#pragma unroll
      for (int kt = 0; kt < 8; ++kt) {
        const short8 a = *(const short8*)&h1buf[lm * 264 + kt * 32 + q * 8];
        aH = mfma16(a, W1hf[kt], aH);
      }
      const floatx4 acc = aI + aH;
#pragma unroll
      for (int r = 0; r < 4; ++r) gatebuf[(wv * 16 + q * 4 + r) * 20 + lm] = acc[r];
    }
    __syncthreads();  // B3

    // ---- sync1: cell1 + publish, spin+read+scatter ----
    if (g == 0) {
      unsigned long long pk = 0;
#pragma unroll
      for (int r = 0; r < 4; ++r) {
        const int m = q * 4 + r;
        const float iv = gatebuf[((ht * 4 + 0) * 16 + m) * 20 + lm];
        const float fv = gatebuf[((ht * 4 + 1) * 16 + m) * 20 + lm];
        const float gv = gatebuf[((ht * 4 + 2) * 16 + m) * 20 + lm];
        const float ov = gatebuf[((ht * 4 + 3) * 16 + m) * 20 + lm];
        const float cn = sigm(fv) * cst1[r] + sigm(iv) * tanh_fast(gv);
        cst1[r] = cn;
        pk |= (unsigned long long)f2bf(sigm(ov) * tanh_fast(cn)) << (16 * r);
      }
      __hip_atomic_store(&ex[gbase1 + (size_t)hcol * 4 + q], pk, __ATOMIC_RELAXED,
                         __HIP_MEMORY_SCOPE_AGENT);
      __asm__ __volatile__("" ::: "memory");
      __builtin_amdgcn_s_waitcnt(0);
      __asm__ __volatile__("" ::: "memory");
      if (lane == 0)
        __hip_atomic_store(&((unsigned int*)flagsQ)[(fi1 + slice) * 2 + ht], (unsigned)(t + 1),
                           __ATOMIC_RELAXED, __HIP_MEMORY_SCOPE_AGENT);
    }
    {
      const unsigned long long* fq = &flagsQ[fi1 + wv];
      unsigned long long fvq;
      do {
        fvq = __hip_atomic_load(fq, __ATOMIC_ACQUIRE, __HIP_MEMORY_SCOPE_AGENT);
      } while ((int)(fvq & 0xffffffffu) < t + 1 || (int)(fvq >> 32) < t + 1);
      const unsigned long long v0 =
          __hip_atomic_load(&ex[gbase1 + 2 * tid], __ATOMIC_RELAXED, __HIP_MEMORY_SCOPE_AGENT);
      const unsigned long long v1 =
          __hip_atomic_load(&ex[gbase1 + 2 * tid + 1], __ATOMIC_RELAXED, __HIP_MEMORY_SCOPE_AGENT);
#pragma unroll
      for (int r = 0; r < 4; ++r) {
        h1buf[(rq * 4 + r) * 264 + rcol] = (unsigned short)(v0 >> (16 * r));
        h1buf[((rq + 1) * 4 + r) * 264 + rcol] = (unsigned short)(v1 >> (16 * r));
      }
    }
    __syncthreads();  // B4: h1buf ready

    // ---- phase F: attention (replicated per wg) ----
    floatx4 ta = (floatx4){tahbv, tahbv, tahbv, tahbv};
#pragma unroll
    for (int kt = 0; kt < 8; ++kt) {
      const short8 a = *(const short8*)&h1buf[lm * 264 + kt * 32 + q * 8];
      ta = mfma16(a, *(const short8*)&tahWs[fcol * 264 + kt * 32 + q * 8], ta);
    }
#pragma unroll
    for (int r = 0; r < 4; ++r) totB[(q * 4 + r) * 136 + fcol] = f2bf(ta[r]);
    __syncthreads();  // B5
    floatx4 sa = (floatx4){tabv, tabv, tabv, tabv};
#pragma unroll
    for (int kt = 0; kt < 4; ++kt) {
      const short8 a = *(const short8*)&totB[lm * 136 + kt * 32 + q * 8];
      sa = mfma16(a, *(const short8*)&taWs[fcol * 136 + kt * 32 + q * 8], sa);
    }
#pragma unroll
    for (int r = 0; r < 4; ++r) {
      const float e = __expf(fmaxf(sa[r], 0.f));  // relu(spre) in [0,~1]: safe
      num[r] += e * ta[r];
      den[r] += e;
    }
    // totB reads complete before next step's writes: B1..B4 intervene.

#pragma unroll
    for (int kt = 0; kt < 4; ++kt) axf[kt] = axn[kt];
  }

  // ---- out[b] = sum_f (num/den)*outW ----
  float* red = gatebuf;  // reuse
#pragma unroll
  for (int r = 0; r < 4; ++r) red[(q * 4 + r) * 136 + fcol] = (num[r] / den[r]) * outWv;
  __syncthreads();
  if (slice == 0 && tid < 16) {
    float s = 0.f;
    for (int k = 0; k < 128; ++k) s += red[tid * 136 + k];
    out[b0 + tid] = s;
  }
}

// ---------- host ----------
extern "C" void kernel_launch(void* const* d_in, const int* in_sizes, int n_in,
                              void* d_out, int out_size, void* d_ws, size_t ws_size,
                              hipStream_t stream) {
  (void)in_sizes; (void)n_in; (void)out_size; (void)ws_size;
  const float* x    = (const float*)d_in[0];
  const float* bng  = (const float*)d_in[1];
  const float* bnb  = (const float*)d_in[2];
  const float* bnm  = (const float*)d_in[3];
  const float* bnv  = (const float*)d_in[4];
  const float* saW  = (const float*)d_in[5];
  const float* sab  = (const float*)d_in[6];
  const float* inW  = (const float*)d_in[7];
  const float* inb  = (const float*)d_in[8];
  const float* Wih0 = (const float*)d_in[9];
  const float* Whh0 = (const float*)d_in[10];
  const float* bih0 = (const float*)d_in[11];
  const float* bhh0 = (const float*)d_in[12];
  const float* Wih1 = (const float*)d_in[13];
  const float* Whh1 = (const float*)d_in[14];
  const float* bih1 = (const float*)d_in[15];
  const float* bhh1 = (const float*)d_in[16];
  const float* tahW = (const float*)d_in[17];
  const float* tahb = (const float*)d_in[18];
  const float* taW  = (const float*)d_in[19];
  const float* tab  = (const float*)d_in[20];
  const float* outW = (const float*)d_in[21];
  float* out = (float*)d_out;

  char* ws = (char*)d_ws;
  size_t off = 0;
  auto alloc = [&](size_t bytes) {
    char* p = ws + off;
    off += (bytes + 255) & ~(size_t)255;
    return p;
  };
  unsigned short* Wc    = (unsigned short*)alloc((size_t)1024 * 128 * 2);
  float* bc             = (float*)alloc(1024 * 4);
  float* b1             = (float*)alloc(1024 * 4);
  unsigned short* Whh0b = (unsigned short*)alloc((size_t)1024 * 256 * 2);
  unsigned short* Whh1b = (unsigned short*)alloc((size_t)1024 * 256 * 2);
  unsigned short* Wih1b = (unsigned short*)alloc((size_t)1024 * 256 * 2);
  unsigned short* tahWb = (unsigned short*)alloc((size_t)128 * 256 * 2);
  unsigned short* taWb  = (unsigned short*)alloc((size_t)128 * 128 * 2);
  unsigned short* xs    = (unsigned short*)alloc((size_t)131072 * 128 * 2);
  unsigned long long* ex     = (unsigned long long*)alloc((size_t)2 * 2 * 16 * 1024 * 8);
  unsigned long long* flagsQ = (unsigned long long*)alloc((size_t)2 * 2 * 16 * 8 * 8);

  hipMemsetAsync(flagsQ, 0, (size_t)2 * 2 * 16 * 8 * 8, stream);
  hipLaunchKernelGGL(wc_kernel, dim3(1024), dim3(128), 0, stream, Wih0, inW, inb, bih0, bhh0, Wc, bc);
  hipLaunchKernelGGL(cvt_kernel, dim3(1024), dim3(256), 0, stream, Whh0b, Whh0, 262144);
  hipLaunchKernelGGL(cvt_kernel, dim3(1024), dim3(256), 0, stream, Whh1b, Whh1, 262144);
  hipLaunchKernelGGL(cvt_kernel, dim3(1024), dim3(256), 0, stream, Wih1b, Wih1, 262144);
  hipLaunchKernelGGL(cvt_kernel, dim3(128), dim3(256), 0, stream, tahWb, tahW, 32768);
  hipLaunchKernelGGL(cvt_kernel, dim3(64), dim3(256), 0, stream, taWb, taW, 16384);
  hipLaunchKernelGGL(addb_kernel, dim3(4), dim3(256), 0, stream, b1, bih1, bhh1, 1024);
  hipLaunchKernelGGL(bnsa_kernel, dim3(1024), dim3(128), 0, stream, x, bng, bnb, bnm, bnv, saW, sab, xs, 128);
  hipLaunchKernelGGL(persist_kernel, dim3(128), dim3(512), 0, stream, xs, Wc, bc, Whh0b, Wih1b,
                     b1, Whh1b, tahWb, tahb, taWb, tab, outW, ex, flagsQ, out);
}

// Round 6
// 3731.026 us; speedup vs baseline: 6.7987x; 6.7987x over previous
//
#include <hip/hip_runtime.h>

typedef __attribute__((ext_vector_type(8))) short short8;
typedef __attribute__((ext_vector_type(4))) float floatx4;
typedef __attribute__((ext_vector_type(2))) unsigned long long ull2;

// ---------- helpers ----------
__device__ __forceinline__ unsigned short f2bf(float f) {
  unsigned int u = __float_as_uint(f);
  unsigned int lsb = (u >> 16) & 1u;
  u += 0x7fffu + lsb;  // round-to-nearest-even
  return (unsigned short)(u >> 16);
}
__device__ __forceinline__ float bf2f(unsigned short u) {
  unsigned int x = ((unsigned int)u) << 16;
  return __uint_as_float(x);
}
__device__ __forceinline__ float sigm(float x) { return 1.f / (1.f + __expf(-x)); }
__device__ __forceinline__ float tanh_fast(float x) { return 2.f / (1.f + __expf(-2.f * x)) - 1.f; }
__device__ __forceinline__ floatx4 mfma16(short8 a, short8 b, floatx4 c) {
  return __builtin_amdgcn_mfma_f32_16x16x32_bf16(a, b, c, 0, 0, 0);
}

// ---------- prep ----------
__global__ void wc_kernel(const float* __restrict__ Wih0, const float* __restrict__ inW,
                          const float* __restrict__ inb, const float* __restrict__ bih0,
                          const float* __restrict__ bhh0, unsigned short* __restrict__ Wc,
                          float* __restrict__ bc) {
  const int n = blockIdx.x;   // 0..1023
  const int k = threadIdx.x;  // 0..127
  float a = 0.f;
  for (int j = 0; j < 256; ++j) a += Wih0[n * 256 + j] * inW[j * 128 + k];
  Wc[n * 128 + k] = f2bf(a);
  if (k == 0) {
    float bsum = bih0[n] + bhh0[n];
    for (int j = 0; j < 256; ++j) bsum += Wih0[n * 256 + j] * inb[j];
    bc[n] = bsum;
  }
}

__global__ void cvt_kernel(unsigned short* __restrict__ dst, const float* __restrict__ src, int n) {
  int i = blockIdx.x * 256 + threadIdx.x;
  if (i < n) dst[i] = f2bf(src[i]);
}

__global__ void addb_kernel(float* __restrict__ b1, const float* __restrict__ xa,
                            const float* __restrict__ ya, int n) {
  int i = blockIdx.x * 256 + threadIdx.x;
  if (i < n) b1[i] = xa[i] + ya[i];
}

// ---------- BatchNorm + spatial attention ----------
__global__ __launch_bounds__(128) void bnsa_kernel(
    const float* __restrict__ x, const float* __restrict__ gamma,
    const float* __restrict__ beta, const float* __restrict__ mean,
    const float* __restrict__ var, const float* __restrict__ saW,
    const float* __restrict__ sab, unsigned short* __restrict__ xs, int rowsPerWg) {
  __shared__ unsigned short saT[128 * 128];  // bf16 [k][j] = saW[j][k]
  __shared__ float xbuf[128];
  __shared__ float ebuf[128];
  const int j = threadIdx.x;
  for (int k = 0; k < 128; ++k) saT[k * 128 + j] = f2bf(saW[j * 128 + k]);
  const float g = gamma[j], bt = beta[j], mn = mean[j];
  const float istd = rsqrtf(var[j] + 1e-5f);
  const float sb = sab[j];
  __syncthreads();
  const long row0 = (long)blockIdx.x * rowsPerWg;
  for (int it = 0; it < rowsPerWg; ++it) {
    const long row = row0 + it;
    const float xv = x[row * 128 + j];
    const float xb = (xv - mn) * istd * g + bt;
    xbuf[j] = xb;
    __syncthreads();
    float s = sb;
#pragma unroll 8
    for (int k = 0; k < 128; ++k) s += xbuf[k] * bf2f(saT[k * 128 + j]);
    const float e = __expf(sigm(s));
    ebuf[j] = e;
    __syncthreads();
    float sum = 0.f;
#pragma unroll 8
    for (int k = 0; k < 128; ++k) sum += ebuf[k];
    xs[row * 128 + j] = f2bf(xb * (e / sum));
    __syncthreads();
  }
}

// ---------- N-split persistent kernel, single fused MALL exchange per step ----------
// 128 wgs = 16 batch-groups x 8 slices; 512 thr (8 waves), wave wv: g=wv&3, ht=wv>>2.
// Iter t computes gates0(t) [h0_{t-1}] and gates1(t-1) [h0_{t-1},h1_{t-2}] back-to-back,
// then cell0 (g==0) -> h0_t and cell1 (g==1) -> h1_{t-1}, published TOGETHER in one 16KB
// exchange. Writers: relaxed agent atomics + s_waitcnt + relaxed flag (no fence/wbl2).
// Readers: relaxed flag poll (no acquire -> no cache inv) + coalesced sc0+sc1 dwordx4
// loads straight from MALL. Attention lags one step (h1_{t-1}); 513 iterations.
__global__ __launch_bounds__(512, 2) void persist_kernel(
    const unsigned short* __restrict__ xs,  // [B,T,128] bf16
    const unsigned short* __restrict__ Wc, const float* __restrict__ bc,
    const unsigned short* __restrict__ Whh0,
    const unsigned short* __restrict__ Wih1, const float* __restrict__ b1,
    const unsigned short* __restrict__ Whh1,
    const unsigned short* __restrict__ tahWg, const float* __restrict__ tahb,
    const unsigned short* __restrict__ taWg, const float* __restrict__ tab,
    const float* __restrict__ outW,
    unsigned long long* __restrict__ ex,  // [2 parity][16 groups][2048 qw] (h0:0..1023, h1:1024..2047)
    unsigned int* __restrict__ flags32,   // [2][16][8 slices][4 pubs]
    float* __restrict__ out) {
  __shared__ unsigned short tahWs[128 * 264];  // [f][k], k<256
  __shared__ unsigned short taWs[128 * 136];   // [f][j], j<128
  __shared__ unsigned short h0buf[16 * 264];
  __shared__ unsigned short h1buf[16 * 264];
  __shared__ float gatebuf[2][8 * 16 * 20];    // [layer][gateblk*16+m][20]
  __shared__ unsigned short totB[16 * 136];

  const int tid = threadIdx.x;
  const int wv = tid >> 6, lane = tid & 63;
  const int lm = lane & 15, q = lane >> 4;
  const int slice = blockIdx.x >> 4, group = blockIdx.x & 15;
  const int g = wv & 3, ht = wv >> 2;
  const int b0 = group * 16;
  const int hcol = slice * 32 + ht * 16 + lm;
  const int ng = g * 256 + hcol;
  const int fcol = wv * 16 + lm;

  for (int i = tid; i < 128 * 256; i += 512) tahWs[(i >> 8) * 264 + (i & 255)] = tahWg[i];
  for (int i = tid; i < 128 * 128; i += 512) taWs[(i >> 7) * 136 + (i & 127)] = taWg[i];
  for (int i = tid; i < 16 * 264; i += 512) { h0buf[i] = 0; h1buf[i] = 0; }

  // register-resident weight B-frags (loaded once)
  short8 Wcf[4], W0f[8], W1if[8], W1hf[8];
#pragma unroll
  for (int kt = 0; kt < 4; ++kt) Wcf[kt] = *(const short8*)&Wc[(size_t)ng * 128 + kt * 32 + q * 8];
#pragma unroll
  for (int kt = 0; kt < 8; ++kt) {
    W0f[kt] = *(const short8*)&Whh0[(size_t)ng * 256 + kt * 32 + q * 8];
    W1if[kt] = *(const short8*)&Wih1[(size_t)ng * 256 + kt * 32 + q * 8];
    W1hf[kt] = *(const short8*)&Whh1[(size_t)ng * 256 + kt * 32 + q * 8];
  }
  const float bcv = bc[ng], b1v = b1[ng];
  const float tahbv = tahb[fcol], tabv = tab[fcol], outWv = outW[fcol];

  floatx4 cst0 = (floatx4){0.f, 0.f, 0.f, 0.f};  // live in g==0 waves
  floatx4 cst1 = (floatx4){0.f, 0.f, 0.f, 0.f};  // live in g==1 waves
  float num[4] = {0.f, 0.f, 0.f, 0.f}, den[4] = {0.f, 0.f, 0.f, 0.f};

  const unsigned short* xrow = xs + (size_t)(b0 + lm) * 65536 + q * 8;
  short8 axf[4], axn[4];
#pragma unroll
  for (int kt = 0; kt < 4; ++kt) axf[kt] = *(const short8*)(xrow + kt * 32);

  // reader assignment: thread tid -> col rcol = tid>>1, row-quads rq, rq+1
  const int rcol = tid >> 1;
  const int rq = (tid & 1) * 2;
  __syncthreads();

  for (int t = 0; t <= 512; ++t) {
    const int p = t & 1;
    const size_t base = ((size_t)p * 16 + group) * 2048;
    const int fbase = ((p * 16 + group) * 8 + slice) * 4;
    const unsigned flagv = (unsigned)(t + 1);

    // ---- gates0(t) = xs_t @ Wc^T + h0_{t-1} @ Whh0^T + bc ----
    {
      floatx4 aW = (floatx4){0.f, 0.f, 0.f, 0.f};
      floatx4 aH = (floatx4){bcv, bcv, bcv, bcv};
#pragma unroll
      for (int kt = 0; kt < 4; ++kt) aW = mfma16(axf[kt], Wcf[kt], aW);
#pragma unroll
      for (int kt = 0; kt < 8; ++kt) {
        const short8 a = *(const short8*)&h0buf[lm * 264 + kt * 32 + q * 8];
        aH = mfma16(a, W0f[kt], aH);
      }
      const floatx4 acc = aW + aH;
#pragma unroll
      for (int r = 0; r < 4; ++r) gatebuf[0][(wv * 16 + q * 4 + r) * 20 + lm] = acc[r];
    }
    {  // prefetch next xs frags (clamped)
      const size_t tn = (t < 511) ? t + 1 : 511;
#pragma unroll
      for (int kt = 0; kt < 4; ++kt) axn[kt] = *(const short8*)(xrow + tn * 128 + kt * 32);
    }
    // ---- gates1(t-1) = h0_{t-1} @ Wih1^T + h1_{t-2} @ Whh1^T + b1 ----
    {
      floatx4 aI = (floatx4){b1v, b1v, b1v, b1v};
      floatx4 aH = (floatx4){0.f, 0.f, 0.f, 0.f};
#pragma unroll
      for (int kt = 0; kt < 8; ++kt) {
        const short8 a = *(const short8*)&h0buf[lm * 264 + kt * 32 + q * 8];
        aI = mfma16(a, W1if[kt], aI);
      }
#pragma unroll
      for (int kt = 0; kt < 8; ++kt) {
        const short8 a = *(const short8*)&h1buf[lm * 264 + kt * 32 + q * 8];
        aH = mfma16(a, W1hf[kt], aH);
      }
      const floatx4 acc = aI + aH;
#pragma unroll
      for (int r = 0; r < 4; ++r) gatebuf[1][(wv * 16 + q * 4 + r) * 20 + lm] = acc[r];
    }
    __syncthreads();  // B1: both gatebufs complete; all h0/h1buf reads done

    // ---- cells + publish (one combined exchange) ----
    if (g == 0) {  // cell0 -> h0_t
      unsigned long long pk = 0;
#pragma unroll
      for (int r = 0; r < 4; ++r) {
        const int m = q * 4 + r;
        const float iv = gatebuf[0][((ht * 4 + 0) * 16 + m) * 20 + lm];
        const float fv = gatebuf[0][((ht * 4 + 1) * 16 + m) * 20 + lm];
        const float gv = gatebuf[0][((ht * 4 + 2) * 16 + m) * 20 + lm];
        const float ov = gatebuf[0][((ht * 4 + 3) * 16 + m) * 20 + lm];
        const float cn = sigm(fv) * cst0[r] + sigm(iv) * tanh_fast(gv);
        cst0[r] = cn;
        pk |= (unsigned long long)f2bf(sigm(ov) * tanh_fast(cn)) << (16 * r);
      }
      __hip_atomic_store(&ex[base + (size_t)hcol * 4 + q], pk, __ATOMIC_RELAXED,
                         __HIP_MEMORY_SCOPE_AGENT);
      __builtin_amdgcn_s_waitcnt(0);  // data at coherence point
      if (lane == 0)
        __hip_atomic_store(&flags32[fbase + ht], flagv, __ATOMIC_RELAXED,
                           __HIP_MEMORY_SCOPE_AGENT);
    } else if (g == 1) {  // cell1 -> h1_{t-1} (t==0 publishes h1_{-1}=0)
      unsigned long long pk = 0;
      if (t > 0) {
#pragma unroll
        for (int r = 0; r < 4; ++r) {
          const int m = q * 4 + r;
          const float iv = gatebuf[1][((ht * 4 + 0) * 16 + m) * 20 + lm];
          const float fv = gatebuf[1][((ht * 4 + 1) * 16 + m) * 20 + lm];
          const float gv = gatebuf[1][((ht * 4 + 2) * 16 + m) * 20 + lm];
          const float ov = gatebuf[1][((ht * 4 + 3) * 16 + m) * 20 + lm];
          const float cn = sigm(fv) * cst1[r] + sigm(iv) * tanh_fast(gv);
          cst1[r] = cn;
          pk |= (unsigned long long)f2bf(sigm(ov) * tanh_fast(cn)) << (16 * r);
        }
      }
      __hip_atomic_store(&ex[base + 1024 + (size_t)hcol * 4 + q], pk, __ATOMIC_RELAXED,
                         __HIP_MEMORY_SCOPE_AGENT);
      __builtin_amdgcn_s_waitcnt(0);
      if (lane == 0)
        __hip_atomic_store(&flags32[fbase + 2 + ht], flagv, __ATOMIC_RELAXED,
                           __HIP_MEMORY_SCOPE_AGENT);
    }

    // ---- spin (relaxed: no cache invalidates); wave wv sources slice wv ----
    {
      const unsigned long long* fq =
          (const unsigned long long*)&flags32[((p * 16 + group) * 8 + wv) * 4];
      unsigned long long f0, f1;
      do {
        f0 = __hip_atomic_load(fq, __ATOMIC_RELAXED, __HIP_MEMORY_SCOPE_AGENT);
        f1 = __hip_atomic_load(fq + 1, __ATOMIC_RELAXED, __HIP_MEMORY_SCOPE_AGENT);
      } while ((unsigned)(f0 & 0xffffffffu) < flagv || (unsigned)(f0 >> 32) < flagv ||
               (unsigned)(f1 & 0xffffffffu) < flagv || (unsigned)(f1 >> 32) < flagv);
    }
    // ---- bulk read: coalesced MALL-direct loads (bypass L1+L2), scatter to LDS ----
    {
      ull2 a, b;
      const unsigned long long* p0 = ex + base + 2 * tid;
      const unsigned long long* p1 = ex + base + 1024 + 2 * tid;
      asm volatile(
          "global_load_dwordx4 %0, %2, off sc0 sc1\n\t"
          "global_load_dwordx4 %1, %3, off sc0 sc1\n\t"
          "s_waitcnt vmcnt(0)"
          : "=&v"(a), "=&v"(b)
          : "v"(p0), "v"(p1)
          : "memory");
#pragma unroll
      for (int r = 0; r < 4; ++r) {
        h0buf[(rq * 4 + r) * 264 + rcol] = (unsigned short)(a.x >> (16 * r));
        h0buf[((rq + 1) * 4 + r) * 264 + rcol] = (unsigned short)(a.y >> (16 * r));
        h1buf[(rq * 4 + r) * 264 + rcol] = (unsigned short)(b.x >> (16 * r));
        h1buf[((rq + 1) * 4 + r) * 264 + rcol] = (unsigned short)(b.y >> (16 * r));
      }
    }
    __syncthreads();  // B2: h0buf=h0_t, h1buf=h1_{t-1}

    // ---- attention on h1_{t-1} (skip t==0: h1_{-1} is not a real step) ----
    floatx4 ta;
    if (t >= 1) {
      ta = (floatx4){tahbv, tahbv, tahbv, tahbv};
#pragma unroll
      for (int kt = 0; kt < 8; ++kt) {
        const short8 a = *(const short8*)&h1buf[lm * 264 + kt * 32 + q * 8];
        ta = mfma16(a, *(const short8*)&tahWs[fcol * 264 + kt * 32 + q * 8], ta);
      }
#pragma unroll
      for (int r = 0; r < 4; ++r) totB[(q * 4 + r) * 136 + fcol] = f2bf(ta[r]);
    }
    __syncthreads();  // B3: totB visible
    if (t >= 1) {
      floatx4 sa = (floatx4){tabv, tabv, tabv, tabv};
#pragma unroll
      for (int kt = 0; kt < 4; ++kt) {
        const short8 a = *(const short8*)&totB[lm * 136 + kt * 32 + q * 8];
        sa = mfma16(a, *(const short8*)&taWs[fcol * 136 + kt * 32 + q * 8], sa);
      }
#pragma unroll
      for (int r = 0; r < 4; ++r) {
        const float e = __expf(fmaxf(sa[r], 0.f));  // relu(spre) in [0,~1]: safe
        num[r] += e * ta[r];
        den[r] += e;
      }
    }
    // totB reads precede next iter's totB writes (B1,B2 of next iter intervene)

#pragma unroll
    for (int kt = 0; kt < 4; ++kt) axf[kt] = axn[kt];
  }

  // ---- out[b] = sum_f (num/den)*outW ----
  float* red = &gatebuf[0][0];  // reuse (>= 16*136 floats)
#pragma unroll
  for (int r = 0; r < 4; ++r) red[(q * 4 + r) * 136 + fcol] = (num[r] / den[r]) * outWv;
  __syncthreads();
  if (slice == 0 && tid < 16) {
    float s = 0.f;
    for (int k = 0; k < 128; ++k) s += red[tid * 136 + k];
    out[b0 + tid] = s;
  }
}

// ---------- host ----------
extern "C" void kernel_launch(void* const* d_in, const int* in_sizes, int n_in,
                              void* d_out, int out_size, void* d_ws, size_t ws_size,
                              hipStream_t stream) {
  (void)in_sizes; (void)n_in; (void)out_size; (void)ws_size;
  const float* x    = (const float*)d_in[0];
  const float* bng  = (const float*)d_in[1];
  const float* bnb  = (const float*)d_in[2];
  const float* bnm  = (const float*)d_in[3];
  const float* bnv  = (const float*)d_in[4];
  const float* saW  = (const float*)d_in[5];
  const float* sab  = (const float*)d_in[6];
  const float* inW  = (const float*)d_in[7];
  const float* inb  = (const float*)d_in[8];
  const float* Wih0 = (const float*)d_in[9];
  const float* Whh0 = (const float*)d_in[10];
  const float* bih0 = (const float*)d_in[11];
  const float* bhh0 = (const float*)d_in[12];
  const float* Wih1 = (const float*)d_in[13];
  const float* Whh1 = (const float*)d_in[14];
  const float* bih1 = (const float*)d_in[15];
  const float* bhh1 = (const float*)d_in[16];
  const float* tahW = (const float*)d_in[17];
  const float* tahb = (const float*)d_in[18];
  const float* taW  = (const float*)d_in[19];
  const float* tab  = (const float*)d_in[20];
  const float* outW = (const float*)d_in[21];
  float* out = (float*)d_out;

  char* ws = (char*)d_ws;
  size_t off = 0;
  auto alloc = [&](size_t bytes) {
    char* p = ws + off;
    off += (bytes + 255) & ~(size_t)255;
    return p;
  };
  unsigned short* Wc    = (unsigned short*)alloc((size_t)1024 * 128 * 2);
  float* bc             = (float*)alloc(1024 * 4);
  float* b1             = (float*)alloc(1024 * 4);
  unsigned short* Whh0b = (unsigned short*)alloc((size_t)1024 * 256 * 2);
  unsigned short* Whh1b = (unsigned short*)alloc((size_t)1024 * 256 * 2);
  unsigned short* Wih1b = (unsigned short*)alloc((size_t)1024 * 256 * 2);
  unsigned short* tahWb = (unsigned short*)alloc((size_t)128 * 256 * 2);
  unsigned short* taWb  = (unsigned short*)alloc((size_t)128 * 128 * 2);
  unsigned short* xs    = (unsigned short*)alloc((size_t)131072 * 128 * 2);
  unsigned long long* ex = (unsigned long long*)alloc((size_t)2 * 16 * 2048 * 8);  // 512 KB
  unsigned int* flags32  = (unsigned int*)alloc((size_t)2 * 16 * 8 * 4 * 4);       // 4 KB

  hipMemsetAsync(flags32, 0, (size_t)2 * 16 * 8 * 4 * 4, stream);
  hipLaunchKernelGGL(wc_kernel, dim3(1024), dim3(128), 0, stream, Wih0, inW, inb, bih0, bhh0, Wc, bc);
  hipLaunchKernelGGL(cvt_kernel, dim3(1024), dim3(256), 0, stream, Whh0b, Whh0, 262144);
  hipLaunchKernelGGL(cvt_kernel, dim3(1024), dim3(256), 0, stream, Whh1b, Whh1, 262144);
  hipLaunchKernelGGL(cvt_kernel, dim3(1024), dim3(256), 0, stream, Wih1b, Wih1, 262144);
  hipLaunchKernelGGL(cvt_kernel, dim3(128), dim3(256), 0, stream, tahWb, tahW, 32768);
  hipLaunchKernelGGL(cvt_kernel, dim3(64), dim3(256), 0, stream, taWb, taW, 16384);
  hipLaunchKernelGGL(addb_kernel, dim3(4), dim3(256), 0, stream, b1, bih1, bhh1, 1024);
  hipLaunchKernelGGL(bnsa_kernel, dim3(1024), dim3(128), 0, stream, x, bng, bnb, bnm, bnv, saW, sab, xs, 128);
  hipLaunchKernelGGL(persist_kernel, dim3(128), dim3(512), 0, stream, xs, Wc, bc, Whh0b, Wih1b,
                     b1, Whh1b, tahWb, tahb, taWb, tab, outW, ex, flags32, out);
}

// Round 7
// 2354.465 us; speedup vs baseline: 10.7737x; 1.5847x over previous
//
#include <hip/hip_runtime.h>

typedef __attribute__((ext_vector_type(8))) short short8;
typedef __attribute__((ext_vector_type(4))) float floatx4;
typedef __attribute__((ext_vector_type(2))) unsigned long long ull2;

// ---------- helpers ----------
__device__ __forceinline__ unsigned short f2bf(float f) {
  unsigned int u = __float_as_uint(f);
  unsigned int lsb = (u >> 16) & 1u;
  u += 0x7fffu + lsb;  // round-to-nearest-even
  return (unsigned short)(u >> 16);
}
__device__ __forceinline__ float bf2f(unsigned short u) {
  unsigned int x = ((unsigned int)u) << 16;
  return __uint_as_float(x);
}
__device__ __forceinline__ float sigm(float x) { return 1.f / (1.f + __expf(-x)); }
__device__ __forceinline__ float tanh_fast(float x) { return 2.f / (1.f + __expf(-2.f * x)) - 1.f; }
__device__ __forceinline__ floatx4 mfma16(short8 a, short8 b, floatx4 c) {
  return __builtin_amdgcn_mfma_f32_16x16x32_bf16(a, b, c, 0, 0, 0);
}

// ---------- prep ----------
__global__ void wc_kernel(const float* __restrict__ Wih0, const float* __restrict__ inW,
                          const float* __restrict__ inb, const float* __restrict__ bih0,
                          const float* __restrict__ bhh0, unsigned short* __restrict__ Wc,
                          float* __restrict__ bc) {
  const int n = blockIdx.x;   // 0..1023
  const int k = threadIdx.x;  // 0..127
  float a = 0.f;
  for (int j = 0; j < 256; ++j) a += Wih0[n * 256 + j] * inW[j * 128 + k];
  Wc[n * 128 + k] = f2bf(a);
  if (k == 0) {
    float bsum = bih0[n] + bhh0[n];
    for (int j = 0; j < 256; ++j) bsum += Wih0[n * 256 + j] * inb[j];
    bc[n] = bsum;
  }
}

__global__ void cvt_kernel(unsigned short* __restrict__ dst, const float* __restrict__ src, int n) {
  int i = blockIdx.x * 256 + threadIdx.x;
  if (i < n) dst[i] = f2bf(src[i]);
}

__global__ void addb_kernel(float* __restrict__ b1, const float* __restrict__ xa,
                            const float* __restrict__ ya, int n) {
  int i = blockIdx.x * 256 + threadIdx.x;
  if (i < n) b1[i] = xa[i] + ya[i];
}

// ---------- BatchNorm + spatial attention ----------
__global__ __launch_bounds__(128) void bnsa_kernel(
    const float* __restrict__ x, const float* __restrict__ gamma,
    const float* __restrict__ beta, const float* __restrict__ mean,
    const float* __restrict__ var, const float* __restrict__ saW,
    const float* __restrict__ sab, unsigned short* __restrict__ xs, int rowsPerWg) {
  __shared__ unsigned short saT[128 * 128];  // bf16 [k][j] = saW[j][k]
  __shared__ float xbuf[128];
  __shared__ float ebuf[128];
  const int j = threadIdx.x;
  for (int k = 0; k < 128; ++k) saT[k * 128 + j] = f2bf(saW[j * 128 + k]);
  const float g = gamma[j], bt = beta[j], mn = mean[j];
  const float istd = rsqrtf(var[j] + 1e-5f);
  const float sb = sab[j];
  __syncthreads();
  const long row0 = (long)blockIdx.x * rowsPerWg;
  for (int it = 0; it < rowsPerWg; ++it) {
    const long row = row0 + it;
    const float xv = x[row * 128 + j];
    const float xb = (xv - mn) * istd * g + bt;
    xbuf[j] = xb;
    __syncthreads();
    float s = sb;
#pragma unroll 8
    for (int k = 0; k < 128; ++k) s += xbuf[k] * bf2f(saT[k * 128 + j]);
    const float e = __expf(sigm(s));
    ebuf[j] = e;
    __syncthreads();
    float sum = 0.f;
#pragma unroll 8
    for (int k = 0; k < 128; ++k) sum += ebuf[k];
    xs[row * 128 + j] = f2bf(xb * (e / sum));
    __syncthreads();
  }
}

// ---------- N-split persistent kernel, self-validating MALL exchange ----------
// 128 wgs = 16 batch-groups x 8 slices; 512 thr (8 waves), wave wv: g=wv&3, ht=wv>>2.
// Exchange entry = 16B: [bf16 m0|bf16 m1|seq32][bf16 m2|bf16 m3|seq32] — each 8B half is
// one HW-atomic relaxed agent store (seq never visible without its data). No flags, no
// writer waitcnt. Waves g<2 publish (stores only); waves g>=2 poll by re-issuing the
// coalesced sc0/sc1 16B bulk loads and checking embedded seqs (detect == transfer).
// Parity double-buffer; barrier skew bounds writers to <2 steps ahead. Attention runs on
// h1_{t-2} between publish and poll (off the critical path), tail step after the loop.
__global__ __launch_bounds__(512, 2) void persist_kernel(
    const unsigned short* __restrict__ xs,  // [B,T,128] bf16
    const unsigned short* __restrict__ Wc, const float* __restrict__ bc,
    const unsigned short* __restrict__ Whh0,
    const unsigned short* __restrict__ Wih1, const float* __restrict__ b1,
    const unsigned short* __restrict__ Whh1,
    const unsigned short* __restrict__ tahWg, const float* __restrict__ tahb,
    const unsigned short* __restrict__ taWg, const float* __restrict__ tab,
    const float* __restrict__ outW,
    ull2* __restrict__ ex,  // [2 parity][16 group][2 layer][1024 entries] x 16B = 1 MB
    float* __restrict__ out) {
  __shared__ unsigned short tahWs[128 * 264];  // [f][k], k<256
  __shared__ unsigned short taWs[128 * 136];   // [f][j], j<128
  __shared__ unsigned short h0buf[16 * 264];
  __shared__ unsigned short h1buf[16 * 264];
  __shared__ float gatebuf[2][8 * 16 * 20];
  __shared__ unsigned short totB[16 * 136];

  const int tid = threadIdx.x;
  const int wv = tid >> 6, lane = tid & 63;
  const int lm = lane & 15, q = lane >> 4;
  const int slice = blockIdx.x >> 4, group = blockIdx.x & 15;
  const int g = wv & 3, ht = wv >> 2;
  const int b0 = group * 16;
  const int hcol = slice * 32 + ht * 16 + lm;
  const int ng = g * 256 + hcol;
  const int fcol = wv * 16 + lm;

  for (int i = tid; i < 128 * 256; i += 512) tahWs[(i >> 8) * 264 + (i & 255)] = tahWg[i];
  for (int i = tid; i < 128 * 128; i += 512) taWs[(i >> 7) * 136 + (i & 127)] = taWg[i];
  for (int i = tid; i < 16 * 264; i += 512) { h0buf[i] = 0; h1buf[i] = 0; }

  // register-resident weight B-frags (loaded once)
  short8 Wcf[4], W0f[8], W1if[8], W1hf[8];
#pragma unroll
  for (int kt = 0; kt < 4; ++kt) Wcf[kt] = *(const short8*)&Wc[(size_t)ng * 128 + kt * 32 + q * 8];
#pragma unroll
  for (int kt = 0; kt < 8; ++kt) {
    W0f[kt] = *(const short8*)&Whh0[(size_t)ng * 256 + kt * 32 + q * 8];
    W1if[kt] = *(const short8*)&Wih1[(size_t)ng * 256 + kt * 32 + q * 8];
    W1hf[kt] = *(const short8*)&Whh1[(size_t)ng * 256 + kt * 32 + q * 8];
  }
  const float bcv = bc[ng], b1v = b1[ng];
  const float tahbv = tahb[fcol], tabv = tab[fcol], outWv = outW[fcol];

  floatx4 cst0 = (floatx4){0.f, 0.f, 0.f, 0.f};  // live in g==0 waves
  floatx4 cst1 = (floatx4){0.f, 0.f, 0.f, 0.f};  // live in g==1 waves
  float num[4] = {0.f, 0.f, 0.f, 0.f}, den[4] = {0.f, 0.f, 0.f, 0.f};

  const unsigned short* xrow = xs + (size_t)(b0 + lm) * 65536 + q * 8;
  short8 axf[4], axn[4];
#pragma unroll
  for (int kt = 0; kt < 4; ++kt) axf[kt] = *(const short8*)(xrow + kt * 32);

  // writer entry index: e = (slice>>1)*256 + ((slice&1)*32 + ht*16 + lm)*4 + q
  // (wave's 64 lanes -> 64 consecutive 16B entries = contiguous 1KB burst)
  const int ew = ((slice >> 1) << 8) + (((slice & 1) * 32 + ht * 16 + lm) << 2) + q;
  ull2* const exg = ex + (size_t)group * 2048;  // [2 layer][1024] per parity via +p*32768

  // reader (waves g>=2): thread nt handles entries {j*256+nt} (load j contiguous per wave)
  const int npidx = ((wv >> 2) << 1) | (wv & 1);
  const int nt = npidx * 64 + lane;
  unsigned voBase[8];
#pragma unroll
  for (int L = 0; L < 2; ++L)
#pragma unroll
    for (int j = 0; j < 4; ++j) voBase[L * 4 + j] = (unsigned)((L * 1024 + j * 256 + nt) << 4);
  const int cb = nt >> 2, qq = nt & 3;  // load j -> col j*64+cb, rows qq*4..qq*4+3

  __syncthreads();

  for (int t = 0; t <= 512; ++t) {
    const int p = t & 1;
    const unsigned fvu = (unsigned)(t + 1);

    // ---- gates0(t) = xs_t @ Wc^T + h0_{t-1} @ Whh0^T + bc ----
    {
      floatx4 aW = (floatx4){0.f, 0.f, 0.f, 0.f};
      floatx4 aH = (floatx4){bcv, bcv, bcv, bcv};
#pragma unroll
      for (int kt = 0; kt < 4; ++kt) aW = mfma16(axf[kt], Wcf[kt], aW);
#pragma unroll
      for (int kt = 0; kt < 8; ++kt) {
        const short8 a = *(const short8*)&h0buf[lm * 264 + kt * 32 + q * 8];
        aH = mfma16(a, W0f[kt], aH);
      }
      const floatx4 acc = aW + aH;
#pragma unroll
      for (int r = 0; r < 4; ++r) gatebuf[0][(wv * 16 + q * 4 + r) * 20 + lm] = acc[r];
    }
    {  // prefetch next xs frags (clamped)
      const size_t tn = (t < 511) ? t + 1 : 511;
#pragma unroll
      for (int kt = 0; kt < 4; ++kt) axn[kt] = *(const short8*)(xrow + tn * 128 + kt * 32);
    }
    // ---- gates1(t-1) = h0_{t-1} @ Wih1^T + h1_{t-2} @ Whh1^T + b1 ----
    {
      floatx4 aI = (floatx4){b1v, b1v, b1v, b1v};
      floatx4 aH = (floatx4){0.f, 0.f, 0.f, 0.f};
#pragma unroll
      for (int kt = 0; kt < 8; ++kt) {
        const short8 a = *(const short8*)&h0buf[lm * 264 + kt * 32 + q * 8];
        aI = mfma16(a, W1if[kt], aI);
      }
#pragma unroll
      for (int kt = 0; kt < 8; ++kt) {
        const short8 a = *(const short8*)&h1buf[lm * 264 + kt * 32 + q * 8];
        aH = mfma16(a, W1hf[kt], aH);
      }
      const floatx4 acc = aI + aH;
#pragma unroll
      for (int r = 0; r < 4; ++r) gatebuf[1][(wv * 16 + q * 4 + r) * 20 + lm] = acc[r];
    }
    __syncthreads();  // B1: gatebufs complete; all h0/h1buf reads for gates done

    // ---- cells + fire-and-forget publish (waves g<2) ----
    if (g < 2) {
      const int L = g;  // layer
      unsigned short hb[4];
      if (L == 0) {  // cell0 -> h0_t
#pragma unroll
        for (int r = 0; r < 4; ++r) {
          const int m = q * 4 + r;
          const float iv = gatebuf[0][((ht * 4 + 0) * 16 + m) * 20 + lm];
          const float fv = gatebuf[0][((ht * 4 + 1) * 16 + m) * 20 + lm];
          const float gv = gatebuf[0][((ht * 4 + 2) * 16 + m) * 20 + lm];
          const float ov = gatebuf[0][((ht * 4 + 3) * 16 + m) * 20 + lm];
          const float cn = sigm(fv) * cst0[r] + sigm(iv) * tanh_fast(gv);
          cst0[r] = cn;
          hb[r] = f2bf(sigm(ov) * tanh_fast(cn));
        }
      } else {  // cell1 -> h1_{t-1} (t==0 publishes zeros)
#pragma unroll
        for (int r = 0; r < 4; ++r) hb[r] = 0;
        if (t > 0) {
#pragma unroll
          for (int r = 0; r < 4; ++r) {
            const int m = q * 4 + r;
            const float iv = gatebuf[1][((ht * 4 + 0) * 16 + m) * 20 + lm];
            const float fv = gatebuf[1][((ht * 4 + 1) * 16 + m) * 20 + lm];
            const float gv = gatebuf[1][((ht * 4 + 2) * 16 + m) * 20 + lm];
            const float ov = gatebuf[1][((ht * 4 + 3) * 16 + m) * 20 + lm];
            const float cn = sigm(fv) * cst1[r] + sigm(iv) * tanh_fast(gv);
            cst1[r] = cn;
            hb[r] = f2bf(sigm(ov) * tanh_fast(cn));
          }
        }
      }
      const unsigned long long sq = (unsigned long long)fvu << 32;
      const unsigned long long qlo = (unsigned long long)hb[0] | ((unsigned long long)hb[1] << 16) | sq;
      const unsigned long long qhi = (unsigned long long)hb[2] | ((unsigned long long)hb[3] << 16) | sq;
      unsigned long long* wp =
          (unsigned long long*)(exg + (size_t)p * 32768 + (size_t)L * 1024 + ew);
      __hip_atomic_store(&wp[0], qlo, __ATOMIC_RELAXED, __HIP_MEMORY_SCOPE_AGENT);
      __hip_atomic_store(&wp[1], qhi, __ATOMIC_RELAXED, __HIP_MEMORY_SCOPE_AGENT);
    }

    // ---- attention-total on h1_{t-2} (off critical path; data flies meanwhile) ----
    floatx4 ta;
    if (t >= 2) {
      ta = (floatx4){tahbv, tahbv, tahbv, tahbv};
#pragma unroll
      for (int kt = 0; kt < 8; ++kt) {
        const short8 a = *(const short8*)&h1buf[lm * 264 + kt * 32 + q * 8];
        ta = mfma16(a, *(const short8*)&tahWs[fcol * 264 + kt * 32 + q * 8], ta);
      }
#pragma unroll
      for (int r = 0; r < 4; ++r) totB[(q * 4 + r) * 136 + fcol] = f2bf(ta[r]);
    }
    __syncthreads();  // B2: totB ready; all h1buf reads done (scatter may now overwrite)
    if (t >= 2) {
      floatx4 sa = (floatx4){tabv, tabv, tabv, tabv};
#pragma unroll
      for (int kt = 0; kt < 4; ++kt) {
        const short8 a = *(const short8*)&totB[lm * 136 + kt * 32 + q * 8];
        sa = mfma16(a, *(const short8*)&taWs[fcol * 136 + kt * 32 + q * 8], sa);
      }
#pragma unroll
      for (int r = 0; r < 4; ++r) {
        const float e = __expf(fmaxf(sa[r], 0.f));  // relu(spre) in [0,~1]: safe
        num[r] += e * ta[r];
        den[r] += e;
      }
    }

    // ---- poll+scatter (waves g>=2): detect == transfer, no flags ----
    if (g >= 2) {
      const unsigned pterm = (unsigned)p << 19;  // p*32768 entries *16B
      const unsigned v0o = voBase[0] + pterm, v1o = voBase[1] + pterm;
      const unsigned v2o = voBase[2] + pterm, v3o = voBase[3] + pterm;
      const unsigned v4o = voBase[4] + pterm, v5o = voBase[5] + pterm;
      const unsigned v6o = voBase[6] + pterm, v7o = voBase[7] + pterm;
      ull2 d0, d1, d2, d3, e0, e1, e2, e3;
      unsigned bad;
      do {
        asm volatile(
            "global_load_dwordx4 %0, %8, %16 sc0 sc1\n\t"
            "global_load_dwordx4 %1, %9, %16 sc0 sc1\n\t"
            "global_load_dwordx4 %2, %10, %16 sc0 sc1\n\t"
            "global_load_dwordx4 %3, %11, %16 sc0 sc1\n\t"
            "global_load_dwordx4 %4, %12, %16 sc0 sc1\n\t"
            "global_load_dwordx4 %5, %13, %16 sc0 sc1\n\t"
            "global_load_dwordx4 %6, %14, %16 sc0 sc1\n\t"
            "global_load_dwordx4 %7, %15, %16 sc0 sc1\n\t"
            "s_waitcnt vmcnt(0)"
            : "=&v"(d0), "=&v"(d1), "=&v"(d2), "=&v"(d3),
              "=&v"(e0), "=&v"(e1), "=&v"(e2), "=&v"(e3)
            : "v"(v0o), "v"(v1o), "v"(v2o), "v"(v3o),
              "v"(v4o), "v"(v5o), "v"(v6o), "v"(v7o),
              "s"(exg)
            : "memory");
        bad = ((unsigned)(d0.x >> 32) != fvu) | ((unsigned)(d0.y >> 32) != fvu) |
              ((unsigned)(d1.x >> 32) != fvu) | ((unsigned)(d1.y >> 32) != fvu) |
              ((unsigned)(d2.x >> 32) != fvu) | ((unsigned)(d2.y >> 32) != fvu) |
              ((unsigned)(d3.x >> 32) != fvu) | ((unsigned)(d3.y >> 32) != fvu) |
              ((unsigned)(e0.x >> 32) != fvu) | ((unsigned)(e0.y >> 32) != fvu) |
              ((unsigned)(e1.x >> 32) != fvu) | ((unsigned)(e1.y >> 32) != fvu) |
              ((unsigned)(e2.x >> 32) != fvu) | ((unsigned)(e2.y >> 32) != fvu) |
              ((unsigned)(e3.x >> 32) != fvu) | ((unsigned)(e3.y >> 32) != fvu);
      } while (bad);
      // scatter: load j -> col j*64+cb, rows qq*4..qq*4+3
      {
        const int c0 = cb, c1 = 64 + cb, c2 = 128 + cb, c3 = 192 + cb;
        h0buf[(qq * 4 + 0) * 264 + c0] = (unsigned short)d0.x;
        h0buf[(qq * 4 + 1) * 264 + c0] = (unsigned short)(d0.x >> 16);
        h0buf[(qq * 4 + 2) * 264 + c0] = (unsigned short)d0.y;
        h0buf[(qq * 4 + 3) * 264 + c0] = (unsigned short)(d0.y >> 16);
        h0buf[(qq * 4 + 0) * 264 + c1] = (unsigned short)d1.x;
        h0buf[(qq * 4 + 1) * 264 + c1] = (unsigned short)(d1.x >> 16);
        h0buf[(qq * 4 + 2) * 264 + c1] = (unsigned short)d1.y;
        h0buf[(qq * 4 + 3) * 264 + c1] = (unsigned short)(d1.y >> 16);
        h0buf[(qq * 4 + 0) * 264 + c2] = (unsigned short)d2.x;
        h0buf[(qq * 4 + 1) * 264 + c2] = (unsigned short)(d2.x >> 16);
        h0buf[(qq * 4 + 2) * 264 + c2] = (unsigned short)d2.y;
        h0buf[(qq * 4 + 3) * 264 + c2] = (unsigned short)(d2.y >> 16);
        h0buf[(qq * 4 + 0) * 264 + c3] = (unsigned short)d3.x;
        h0buf[(qq * 4 + 1) * 264 + c3] = (unsigned short)(d3.x >> 16);
        h0buf[(qq * 4 + 2) * 264 + c3] = (unsigned short)d3.y;
        h0buf[(qq * 4 + 3) * 264 + c3] = (unsigned short)(d3.y >> 16);
        h1buf[(qq * 4 + 0) * 264 + c0] = (unsigned short)e0.x;
        h1buf[(qq * 4 + 1) * 264 + c0] = (unsigned short)(e0.x >> 16);
        h1buf[(qq * 4 + 2) * 264 + c0] = (unsigned short)e0.y;
        h1buf[(qq * 4 + 3) * 264 + c0] = (unsigned short)(e0.y >> 16);
        h1buf[(qq * 4 + 0) * 264 + c1] = (unsigned short)e1.x;
        h1buf[(qq * 4 + 1) * 264 + c1] = (unsigned short)(e1.x >> 16);
        h1buf[(qq * 4 + 2) * 264 + c1] = (unsigned short)e1.y;
        h1buf[(qq * 4 + 3) * 264 + c1] = (unsigned short)(e1.y >> 16);
        h1buf[(qq * 4 + 0) * 264 + c2] = (unsigned short)e2.x;
        h1buf[(qq * 4 + 1) * 264 + c2] = (unsigned short)(e2.x >> 16);
        h1buf[(qq * 4 + 2) * 264 + c2] = (unsigned short)e2.y;
        h1buf[(qq * 4 + 3) * 264 + c2] = (unsigned short)(e2.y >> 16);
        h1buf[(qq * 4 + 0) * 264 + c3] = (unsigned short)e3.x;
        h1buf[(qq * 4 + 1) * 264 + c3] = (unsigned short)(e3.x >> 16);
        h1buf[(qq * 4 + 2) * 264 + c3] = (unsigned short)e3.y;
        h1buf[(qq * 4 + 3) * 264 + c3] = (unsigned short)(e3.y >> 16);
      }
    }
    __syncthreads();  // B3: h0buf=h0_t, h1buf=h1_{t-1}

#pragma unroll
    for (int kt = 0; kt < 4; ++kt) axf[kt] = axn[kt];
  }

  // ---- tail: attention on h1_{511} (last receive) ----
  {
    floatx4 ta = (floatx4){tahbv, tahbv, tahbv, tahbv};
#pragma unroll
    for (int kt = 0; kt < 8; ++kt) {
      const short8 a = *(const short8*)&h1buf[lm * 264 + kt * 32 + q * 8];
      ta = mfma16(a, *(const short8*)&tahWs[fcol * 264 + kt * 32 + q * 8], ta);
    }
#pragma unroll
    for (int r = 0; r < 4; ++r) totB[(q * 4 + r) * 136 + fcol] = f2bf(ta[r]);
    __syncthreads();
    floatx4 sa = (floatx4){tabv, tabv, tabv, tabv};
#pragma unroll
    for (int kt = 0; kt < 4; ++kt) {
      const short8 a = *(const short8*)&totB[lm * 136 + kt * 32 + q * 8];
      sa = mfma16(a, *(const short8*)&taWs[fcol * 136 + kt * 32 + q * 8], sa);
    }
#pragma unroll
    for (int r = 0; r < 4; ++r) {
      const float e = __expf(fmaxf(sa[r], 0.f));
      num[r] += e * ta[r];
      den[r] += e;
    }
  }
  __syncthreads();

  // ---- out[b] = sum_f (num/den)*outW ----
  float* red = &gatebuf[0][0];  // reuse (>= 16*136 floats)
#pragma unroll
  for (int r = 0; r < 4; ++r) red[(q * 4 + r) * 136 + fcol] = (num[r] / den[r]) * outWv;
  __syncthreads();
  if (slice == 0 && tid < 16) {
    float s = 0.f;
    for (int k = 0; k < 128; ++k) s += red[tid * 136 + k];
    out[b0 + tid] = s;
  }
}

// ---------- host ----------
extern "C" void kernel_launch(void* const* d_in, const int* in_sizes, int n_in,
                              void* d_out, int out_size, void* d_ws, size_t ws_size,
                              hipStream_t stream) {
  (void)in_sizes; (void)n_in; (void)out_size; (void)ws_size;
  const float* x    = (const float*)d_in[0];
  const float* bng  = (const float*)d_in[1];
  const float* bnb  = (const float*)d_in[2];
  const float* bnm  = (const float*)d_in[3];
  const float* bnv  = (const float*)d_in[4];
  const float* saW  = (const float*)d_in[5];
  const float* sab  = (const float*)d_in[6];
  const float* inW  = (const float*)d_in[7];
  const float* inb  = (const float*)d_in[8];
  const float* Wih0 = (const float*)d_in[9];
  const float* Whh0 = (const float*)d_in[10];
  const float* bih0 = (const float*)d_in[11];
  const float* bhh0 = (const float*)d_in[12];
  const float* Wih1 = (const float*)d_in[13];
  const float* Whh1 = (const float*)d_in[14];
  const float* bih1 = (const float*)d_in[15];
  const float* bhh1 = (const float*)d_in[16];
  const float* tahW = (const float*)d_in[17];
  const float* tahb = (const float*)d_in[18];
  const float* taW  = (const float*)d_in[19];
  const float* tab  = (const float*)d_in[20];
  const float* outW = (const float*)d_in[21];
  float* out = (float*)d_out;

  char* ws = (char*)d_ws;
  size_t off = 0;
  auto alloc = [&](size_t bytes) {
    char* p = ws + off;
    off += (bytes + 255) & ~(size_t)255;
    return p;
  };
  unsigned short* Wc    = (unsigned short*)alloc((size_t)1024 * 128 * 2);
  float* bc             = (float*)alloc(1024 * 4);
  float* b1             = (float*)alloc(1024 * 4);
  unsigned short* Whh0b = (unsigned short*)alloc((size_t)1024 * 256 * 2);
  unsigned short* Whh1b = (unsigned short*)alloc((size_t)1024 * 256 * 2);
  unsigned short* Wih1b = (unsigned short*)alloc((size_t)1024 * 256 * 2);
  unsigned short* tahWb = (unsigned short*)alloc((size_t)128 * 256 * 2);
  unsigned short* taWb  = (unsigned short*)alloc((size_t)128 * 128 * 2);
  unsigned short* xs    = (unsigned short*)alloc((size_t)131072 * 128 * 2);
  ull2* ex              = (ull2*)alloc((size_t)2 * 16 * 2 * 1024 * 16);  // 1 MB

  hipLaunchKernelGGL(wc_kernel, dim3(1024), dim3(128), 0, stream, Wih0, inW, inb, bih0, bhh0, Wc, bc);
  hipLaunchKernelGGL(cvt_kernel, dim3(1024), dim3(256), 0, stream, Whh0b, Whh0, 262144);
  hipLaunchKernelGGL(cvt_kernel, dim3(1024), dim3(256), 0, stream, Whh1b, Whh1, 262144);
  hipLaunchKernelGGL(cvt_kernel, dim3(1024), dim3(256), 0, stream, Wih1b, Wih1, 262144);
  hipLaunchKernelGGL(cvt_kernel, dim3(128), dim3(256), 0, stream, tahWb, tahW, 32768);
  hipLaunchKernelGGL(cvt_kernel, dim3(64), dim3(256), 0, stream, taWb, taW, 16384);
  hipLaunchKernelGGL(addb_kernel, dim3(4), dim3(256), 0, stream, b1, bih1, bhh1, 1024);
  hipLaunchKernelGGL(bnsa_kernel, dim3(1024), dim3(128), 0, stream, x, bng, bnb, bnm, bnv, saW, sab, xs, 128);
  hipLaunchKernelGGL(persist_kernel, dim3(128), dim3(512), 0, stream, xs, Wc, bc, Whh0b, Wih1b,
                     b1, Whh1b, tahWb, tahb, taWb, tab, outW, ex, out);
}

// Round 8
// 2001.492 us; speedup vs baseline: 12.6737x; 1.1764x over previous
//
#include <hip/hip_runtime.h>

typedef __attribute__((ext_vector_type(8))) short short8;
typedef __attribute__((ext_vector_type(4))) float floatx4;
typedef __attribute__((ext_vector_type(2))) unsigned long long ull2;

// ---------- helpers ----------
__device__ __forceinline__ unsigned short f2bf(float f) {
  unsigned int u = __float_as_uint(f);
  unsigned int lsb = (u >> 16) & 1u;
  u += 0x7fffu + lsb;  // round-to-nearest-even
  return (unsigned short)(u >> 16);
}
__device__ __forceinline__ float bf2f(unsigned short u) {
  unsigned int x = ((unsigned int)u) << 16;
  return __uint_as_float(x);
}
__device__ __forceinline__ float sigm(float x) { return 1.f / (1.f + __expf(-x)); }
__device__ __forceinline__ float tanh_fast(float x) { return 2.f / (1.f + __expf(-2.f * x)) - 1.f; }
__device__ __forceinline__ floatx4 mfma16(short8 a, short8 b, floatx4 c) {
  return __builtin_amdgcn_mfma_f32_16x16x32_bf16(a, b, c, 0, 0, 0);
}

// ---------- fused prep: Wc/bc + 5 bf16 converts + b1, one launch ----------
// blocks 0..511: Wc (2 rows each); 512..895: Whh0/Whh1/Wih1 cvt; 896..911: tahW;
// 912..919: taW; 920: b1.
__global__ __launch_bounds__(256) void prep_kernel(
    const float* __restrict__ Wih0, const float* __restrict__ inW,
    const float* __restrict__ inb, const float* __restrict__ bih0,
    const float* __restrict__ bhh0, const float* __restrict__ Whh0,
    const float* __restrict__ Whh1, const float* __restrict__ Wih1,
    const float* __restrict__ tahW, const float* __restrict__ taW,
    const float* __restrict__ bih1, const float* __restrict__ bhh1,
    unsigned short* __restrict__ Wc, float* __restrict__ bc,
    unsigned short* __restrict__ Whh0b, unsigned short* __restrict__ Whh1b,
    unsigned short* __restrict__ Wih1b, unsigned short* __restrict__ tahWb,
    unsigned short* __restrict__ taWb, float* __restrict__ b1) {
  const int b = blockIdx.x, tid = threadIdx.x;
  if (b < 512) {  // Wc = Wih0 @ in_W; bc = Wih0@in_b + bih0 + bhh0
    const int n = b * 2 + (tid >> 7), k = tid & 127;
    float a = 0.f;
    for (int j = 0; j < 256; ++j) a += Wih0[n * 256 + j] * inW[j * 128 + k];
    Wc[n * 128 + k] = f2bf(a);
    if (k == 0) {
      float bs = bih0[n] + bhh0[n];
      for (int j = 0; j < 256; ++j) bs += Wih0[n * 256 + j] * inb[j];
      bc[n] = bs;
    }
  } else if (b < 896) {
    const int bb = b - 512;
    const float* src = (bb < 128) ? Whh0 : (bb < 256) ? Whh1 : Wih1;
    unsigned short* dst = (bb < 128) ? Whh0b : (bb < 256) ? Whh1b : Wih1b;
    const int off = (bb & 127) * 2048 + tid * 8;
    short8 v;
#pragma unroll
    for (int u = 0; u < 8; ++u) v[u] = (short)f2bf(src[off + u]);
    *(short8*)&dst[off] = v;
  } else if (b < 912) {
    const int off = (b - 896) * 2048 + tid * 8;
    short8 v;
#pragma unroll
    for (int u = 0; u < 8; ++u) v[u] = (short)f2bf(tahW[off + u]);
    *(short8*)&tahWb[off] = v;
  } else if (b < 920) {
    const int off = (b - 912) * 2048 + tid * 8;
    short8 v;
#pragma unroll
    for (int u = 0; u < 8; ++u) v[u] = (short)f2bf(taW[off + u]);
    *(short8*)&taWb[off] = v;
  } else {
#pragma unroll
    for (int u = 0; u < 4; ++u) {
      const int i = tid * 4 + u;
      b1[i] = bih1[i] + bhh1[i];
    }
  }
}

// ---------- BatchNorm + spatial attention, MFMA version ----------
// 1024 wgs x 256 thr (4 waves); wg handles 128 rows. saW LDS-resident bf16;
// S = xb @ saW^T + sab via MFMA (wave: 32 rows x all 128 cols -> row-sum in-wave via
// shuffle); alpha = exp(sigm(S))/rowsum; xs = bf16(xb * alpha), staged in LDS for
// coalesced 16B writes.
__global__ __launch_bounds__(256) void bnsa_kernel(
    const float* __restrict__ x, const float* __restrict__ gamma,
    const float* __restrict__ beta, const float* __restrict__ mean,
    const float* __restrict__ var, const float* __restrict__ saW,
    const float* __restrict__ sab, unsigned short* __restrict__ xs) {
  __shared__ unsigned short saWs[128 * 132];  // [n][k] bf16 (reused as xs staging)
  __shared__ unsigned short xbb[128 * 136];   // [m][k] bf16
  const int tid = threadIdx.x;
  const int wv = tid >> 6, lane = tid & 63;
  const int lm = lane & 15, q = lane >> 4;
  const long r0 = (long)blockIdx.x * 128;

  for (int i = tid; i < 16384; i += 256) saWs[(i >> 7) * 132 + (i & 127)] = f2bf(saW[i]);
  {
    const int k0 = tid & 127;
    const float mn = mean[k0];
    const float is = rsqrtf(var[k0] + 1e-5f) * gamma[k0];
    const float bt = beta[k0];
    for (int i = tid; i < 16384; i += 256) {  // stride 256 keeps k fixed per thread
      const int m = i >> 7;
      xbb[m * 136 + k0] = f2bf((x[(r0 + m) * 128 + k0] - mn) * is + bt);
    }
  }
  __syncthreads();

  short8 af[2][4];
#pragma unroll
  for (int mt = 0; mt < 2; ++mt)
#pragma unroll
    for (int kt = 0; kt < 4; ++kt)
      af[mt][kt] = *(const short8*)&xbb[(wv * 32 + mt * 16 + lm) * 136 + kt * 32 + q * 8];

  floatx4 acc[2][8];
#pragma unroll
  for (int nt = 0; nt < 8; ++nt) {
    const float sb = sab[nt * 16 + lm];
    short8 bf[4];
#pragma unroll
    for (int kt = 0; kt < 4; ++kt)
      bf[kt] = *(const short8*)&saWs[(nt * 16 + lm) * 132 + kt * 32 + q * 8];
#pragma unroll
    for (int mt = 0; mt < 2; ++mt) {
      floatx4 a = (floatx4){sb, sb, sb, sb};
#pragma unroll
      for (int kt = 0; kt < 4; ++kt) a = mfma16(af[mt][kt], bf[kt], a);
      acc[mt][nt] = a;
    }
  }
  // e = exp(sigmoid(S)); row sums across the 16 lm lanes (full 128 cols per row)
  float tot[2][4];
#pragma unroll
  for (int mt = 0; mt < 2; ++mt)
#pragma unroll
    for (int r = 0; r < 4; ++r) {
      float p = 0.f;
#pragma unroll
      for (int nt = 0; nt < 8; ++nt) {
        const float e = __expf(sigm(acc[mt][nt][r]));
        acc[mt][nt][r] = e;
        p += e;
      }
      p += __shfl_xor(p, 1);
      p += __shfl_xor(p, 2);
      p += __shfl_xor(p, 4);
      p += __shfl_xor(p, 8);
      tot[mt][r] = p;
    }
  __syncthreads();  // all saWs B-frag reads done -> reuse as staging
  unsigned short* stg = saWs;  // [128][128]
#pragma unroll
  for (int nt = 0; nt < 8; ++nt) {
    const int col = nt * 16 + lm;
    const float mn = mean[col];
    const float is = rsqrtf(var[col] + 1e-5f) * gamma[col];
    const float bt = beta[col];
#pragma unroll
    for (int mt = 0; mt < 2; ++mt)
#pragma unroll
      for (int r = 0; r < 4; ++r) {
        const int row = wv * 32 + mt * 16 + q * 4 + r;  // C/D: row=quad*4+reg, col=lane&15
        const float xb = (x[(r0 + row) * 128 + col] - mn) * is + bt;
        stg[row * 128 + col] = f2bf(xb * (acc[mt][nt][r] / tot[mt][r]));
      }
  }
  __syncthreads();
  for (int i = tid * 8; i < 16384; i += 2048)
    *(short8*)&xs[r0 * 128 + i] = *(const short8*)&stg[i];
}

// ---------- N-split persistent kernel, self-validating MALL exchange ----------
// (unchanged from round 7 — delta this round is prep-only)
__global__ __launch_bounds__(512, 2) void persist_kernel(
    const unsigned short* __restrict__ xs,  // [B,T,128] bf16
    const unsigned short* __restrict__ Wc, const float* __restrict__ bc,
    const unsigned short* __restrict__ Whh0,
    const unsigned short* __restrict__ Wih1, const float* __restrict__ b1,
    const unsigned short* __restrict__ Whh1,
    const unsigned short* __restrict__ tahWg, const float* __restrict__ tahb,
    const unsigned short* __restrict__ taWg, const float* __restrict__ tab,
    const float* __restrict__ outW,
    ull2* __restrict__ ex,  // [2 parity][16 group][2 layer][1024 entries] x 16B = 1 MB
    float* __restrict__ out) {
  __shared__ unsigned short tahWs[128 * 264];  // [f][k], k<256
  __shared__ unsigned short taWs[128 * 136];   // [f][j], j<128
  __shared__ unsigned short h0buf[16 * 264];
  __shared__ unsigned short h1buf[16 * 264];
  __shared__ float gatebuf[2][8 * 16 * 20];
  __shared__ unsigned short totB[16 * 136];

  const int tid = threadIdx.x;
  const int wv = tid >> 6, lane = tid & 63;
  const int lm = lane & 15, q = lane >> 4;
  const int slice = blockIdx.x >> 4, group = blockIdx.x & 15;
  const int g = wv & 3, ht = wv >> 2;
  const int b0 = group * 16;
  const int hcol = slice * 32 + ht * 16 + lm;
  const int ng = g * 256 + hcol;
  const int fcol = wv * 16 + lm;

  for (int i = tid; i < 128 * 256; i += 512) tahWs[(i >> 8) * 264 + (i & 255)] = tahWg[i];
  for (int i = tid; i < 128 * 128; i += 512) taWs[(i >> 7) * 136 + (i & 127)] = taWg[i];
  for (int i = tid; i < 16 * 264; i += 512) { h0buf[i] = 0; h1buf[i] = 0; }

  // register-resident weight B-frags (loaded once)
  short8 Wcf[4], W0f[8], W1if[8], W1hf[8];
#pragma unroll
  for (int kt = 0; kt < 4; ++kt) Wcf[kt] = *(const short8*)&Wc[(size_t)ng * 128 + kt * 32 + q * 8];
#pragma unroll
  for (int kt = 0; kt < 8; ++kt) {
    W0f[kt] = *(const short8*)&Whh0[(size_t)ng * 256 + kt * 32 + q * 8];
    W1if[kt] = *(const short8*)&Wih1[(size_t)ng * 256 + kt * 32 + q * 8];
    W1hf[kt] = *(const short8*)&Whh1[(size_t)ng * 256 + kt * 32 + q * 8];
  }
  const float bcv = bc[ng], b1v = b1[ng];
  const float tahbv = tahb[fcol], tabv = tab[fcol], outWv = outW[fcol];

  floatx4 cst0 = (floatx4){0.f, 0.f, 0.f, 0.f};  // live in g==0 waves
  floatx4 cst1 = (floatx4){0.f, 0.f, 0.f, 0.f};  // live in g==1 waves
  float num[4] = {0.f, 0.f, 0.f, 0.f}, den[4] = {0.f, 0.f, 0.f, 0.f};

  const unsigned short* xrow = xs + (size_t)(b0 + lm) * 65536 + q * 8;
  short8 axf[4], axn[4];
#pragma unroll
  for (int kt = 0; kt < 4; ++kt) axf[kt] = *(const short8*)(xrow + kt * 32);

  // writer entry index: wave's 64 lanes -> 64 consecutive 16B entries (1KB burst)
  const int ew = ((slice >> 1) << 8) + (((slice & 1) * 32 + ht * 16 + lm) << 2) + q;
  ull2* const exg = ex + (size_t)group * 2048;  // [2 layer][1024] per parity via +p*32768

  // reader (waves g>=2): thread nt handles entries {j*256+nt}
  const int npidx = ((wv >> 2) << 1) | (wv & 1);
  const int nt = npidx * 64 + lane;
  unsigned voBase[8];
#pragma unroll
  for (int L = 0; L < 2; ++L)
#pragma unroll
    for (int j = 0; j < 4; ++j) voBase[L * 4 + j] = (unsigned)((L * 1024 + j * 256 + nt) << 4);
  const int cb = nt >> 2, qq = nt & 3;  // load j -> col j*64+cb, rows qq*4..qq*4+3

  __syncthreads();

  for (int t = 0; t <= 512; ++t) {
    const int p = t & 1;
    const unsigned fvu = (unsigned)(t + 1);

    // ---- gates0(t) = xs_t @ Wc^T + h0_{t-1} @ Whh0^T + bc ----
    {
      floatx4 aW = (floatx4){0.f, 0.f, 0.f, 0.f};
      floatx4 aH = (floatx4){bcv, bcv, bcv, bcv};
#pragma unroll
      for (int kt = 0; kt < 4; ++kt) aW = mfma16(axf[kt], Wcf[kt], aW);
#pragma unroll
      for (int kt = 0; kt < 8; ++kt) {
        const short8 a = *(const short8*)&h0buf[lm * 264 + kt * 32 + q * 8];
        aH = mfma16(a, W0f[kt], aH);
      }
      const floatx4 acc = aW + aH;
#pragma unroll
      for (int r = 0; r < 4; ++r) gatebuf[0][(wv * 16 + q * 4 + r) * 20 + lm] = acc[r];
    }
    {  // prefetch next xs frags (clamped)
      const size_t tn = (t < 511) ? t + 1 : 511;
#pragma unroll
      for (int kt = 0; kt < 4; ++kt) axn[kt] = *(const short8*)(xrow + tn * 128 + kt * 32);
    }
    // ---- gates1(t-1) = h0_{t-1} @ Wih1^T + h1_{t-2} @ Whh1^T + b1 ----
    {
      floatx4 aI = (floatx4){b1v, b1v, b1v, b1v};
      floatx4 aH = (floatx4){0.f, 0.f, 0.f, 0.f};
#pragma unroll
      for (int kt = 0; kt < 8; ++kt) {
        const short8 a = *(const short8*)&h0buf[lm * 264 + kt * 32 + q * 8];
        aI = mfma16(a, W1if[kt], aI);
      }
#pragma unroll
      for (int kt = 0; kt < 8; ++kt) {
        const short8 a = *(const short8*)&h1buf[lm * 264 + kt * 32 + q * 8];
        aH = mfma16(a, W1hf[kt], aH);
      }
      const floatx4 acc = aI + aH;
#pragma unroll
      for (int r = 0; r < 4; ++r) gatebuf[1][(wv * 16 + q * 4 + r) * 20 + lm] = acc[r];
    }
    __syncthreads();  // B1: gatebufs complete; all h0/h1buf reads for gates done

    // ---- cells + fire-and-forget publish (waves g<2) ----
    if (g < 2) {
      const int L = g;  // layer
      unsigned short hb[4];
      if (L == 0) {  // cell0 -> h0_t
#pragma unroll
        for (int r = 0; r < 4; ++r) {
          const int m = q * 4 + r;
          const float iv = gatebuf[0][((ht * 4 + 0) * 16 + m) * 20 + lm];
          const float fv = gatebuf[0][((ht * 4 + 1) * 16 + m) * 20 + lm];
          const float gv = gatebuf[0][((ht * 4 + 2) * 16 + m) * 20 + lm];
          const float ov = gatebuf[0][((ht * 4 + 3) * 16 + m) * 20 + lm];
          const float cn = sigm(fv) * cst0[r] + sigm(iv) * tanh_fast(gv);
          cst0[r] = cn;
          hb[r] = f2bf(sigm(ov) * tanh_fast(cn));
        }
      } else {  // cell1 -> h1_{t-1} (t==0 publishes zeros)
#pragma unroll
        for (int r = 0; r < 4; ++r) hb[r] = 0;
        if (t > 0) {
#pragma unroll
          for (int r = 0; r < 4; ++r) {
            const int m = q * 4 + r;
            const float iv = gatebuf[1][((ht * 4 + 0) * 16 + m) * 20 + lm];
            const float fv = gatebuf[1][((ht * 4 + 1) * 16 + m) * 20 + lm];
            const float gv = gatebuf[1][((ht * 4 + 2) * 16 + m) * 20 + lm];
            const float ov = gatebuf[1][((ht * 4 + 3) * 16 + m) * 20 + lm];
            const float cn = sigm(fv) * cst1[r] + sigm(iv) * tanh_fast(gv);
            cst1[r] = cn;
            hb[r] = f2bf(sigm(ov) * tanh_fast(cn));
          }
        }
      }
      const unsigned long long sq = (unsigned long long)fvu << 32;
      const unsigned long long qlo = (unsigned long long)hb[0] | ((unsigned long long)hb[1] << 16) | sq;
      const unsigned long long qhi = (unsigned long long)hb[2] | ((unsigned long long)hb[3] << 16) | sq;
      unsigned long long* wp =
          (unsigned long long*)(exg + (size_t)p * 32768 + (size_t)L * 1024 + ew);
      __hip_atomic_store(&wp[0], qlo, __ATOMIC_RELAXED, __HIP_MEMORY_SCOPE_AGENT);
      __hip_atomic_store(&wp[1], qhi, __ATOMIC_RELAXED, __HIP_MEMORY_SCOPE_AGENT);
    }

    // ---- attention-total on h1_{t-2} (off critical path; data flies meanwhile) ----
    floatx4 ta;
    if (t >= 2) {
      ta = (floatx4){tahbv, tahbv, tahbv, tahbv};
#pragma unroll
      for (int kt = 0; kt < 8; ++kt) {
        const short8 a = *(const short8*)&h1buf[lm * 264 + kt * 32 + q * 8];
        ta = mfma16(a, *(const short8*)&tahWs[fcol * 264 + kt * 32 + q * 8], ta);
      }
#pragma unroll
      for (int r = 0; r < 4; ++r) totB[(q * 4 + r) * 136 + fcol] = f2bf(ta[r]);
    }
    __syncthreads();  // B2: totB ready; all h1buf reads done (scatter may now overwrite)
    if (t >= 2) {
      floatx4 sa = (floatx4){tabv, tabv, tabv, tabv};
#pragma unroll
      for (int kt = 0; kt < 4; ++kt) {
        const short8 a = *(const short8*)&totB[lm * 136 + kt * 32 + q * 8];
        sa = mfma16(a, *(const short8*)&taWs[fcol * 136 + kt * 32 + q * 8], sa);
      }
#pragma unroll
      for (int r = 0; r < 4; ++r) {
        const float e = __expf(fmaxf(sa[r], 0.f));  // relu(spre) in [0,~1]: safe
        num[r] += e * ta[r];
        den[r] += e;
      }
    }

    // ---- poll+scatter (waves g>=2): detect == transfer, no flags ----
    if (g >= 2) {
      const unsigned pterm = (unsigned)p << 19;  // p*32768 entries *16B
      const unsigned v0o = voBase[0] + pterm, v1o = voBase[1] + pterm;
      const unsigned v2o = voBase[2] + pterm, v3o = voBase[3] + pterm;
      const unsigned v4o = voBase[4] + pterm, v5o = voBase[5] + pterm;
      const unsigned v6o = voBase[6] + pterm, v7o = voBase[7] + pterm;
      ull2 d0, d1, d2, d3, e0, e1, e2, e3;
      unsigned bad;
      do {
        asm volatile(
            "global_load_dwordx4 %0, %8, %16 sc0 sc1\n\t"
            "global_load_dwordx4 %1, %9, %16 sc0 sc1\n\t"
            "global_load_dwordx4 %2, %10, %16 sc0 sc1\n\t"
            "global_load_dwordx4 %3, %11, %16 sc0 sc1\n\t"
            "global_load_dwordx4 %4, %12, %16 sc0 sc1\n\t"
            "global_load_dwordx4 %5, %13, %16 sc0 sc1\n\t"
            "global_load_dwordx4 %6, %14, %16 sc0 sc1\n\t"
            "global_load_dwordx4 %7, %15, %16 sc0 sc1\n\t"
            "s_waitcnt vmcnt(0)"
            : "=&v"(d0), "=&v"(d1), "=&v"(d2), "=&v"(d3),
              "=&v"(e0), "=&v"(e1), "=&v"(e2), "=&v"(e3)
            : "v"(v0o), "v"(v1o), "v"(v2o), "v"(v3o),
              "v"(v4o), "v"(v5o), "v"(v6o), "v"(v7o),
              "s"(exg)
            : "memory");
        bad = ((unsigned)(d0.x >> 32) != fvu) | ((unsigned)(d0.y >> 32) != fvu) |
              ((unsigned)(d1.x >> 32) != fvu) | ((unsigned)(d1.y >> 32) != fvu) |
              ((unsigned)(d2.x >> 32) != fvu) | ((unsigned)(d2.y >> 32) != fvu) |
              ((unsigned)(d3.x >> 32) != fvu) | ((unsigned)(d3.y >> 32) != fvu) |
              ((unsigned)(e0.x >> 32) != fvu) | ((unsigned)(e0.y >> 32) != fvu) |
              ((unsigned)(e1.x >> 32) != fvu) | ((unsigned)(e1.y >> 32) != fvu) |
              ((unsigned)(e2.x >> 32) != fvu) | ((unsigned)(e2.y >> 32) != fvu) |
              ((unsigned)(e3.x >> 32) != fvu) | ((unsigned)(e3.y >> 32) != fvu);
      } while (bad);
      // scatter: load j -> col j*64+cb, rows qq*4..qq*4+3
      {
        const int c0 = cb, c1 = 64 + cb, c2 = 128 + cb, c3 = 192 + cb;
        h0buf[(qq * 4 + 0) * 264 + c0] = (unsigned short)d0.x;
        h0buf[(qq * 4 + 1) * 264 + c0] = (unsigned short)(d0.x >> 16);
        h0buf[(qq * 4 + 2) * 264 + c0] = (unsigned short)d0.y;
        h0buf[(qq * 4 + 3) * 264 + c0] = (unsigned short)(d0.y >> 16);
        h0buf[(qq * 4 + 0) * 264 + c1] = (unsigned short)d1.x;
        h0buf[(qq * 4 + 1) * 264 + c1] = (unsigned short)(d1.x >> 16);
        h0buf[(qq * 4 + 2) * 264 + c1] = (unsigned short)d1.y;
        h0buf[(qq * 4 + 3) * 264 + c1] = (unsigned short)(d1.y >> 16);
        h0buf[(qq * 4 + 0) * 264 + c2] = (unsigned short)d2.x;
        h0buf[(qq * 4 + 1) * 264 + c2] = (unsigned short)(d2.x >> 16);
        h0buf[(qq * 4 + 2) * 264 + c2] = (unsigned short)d2.y;
        h0buf[(qq * 4 + 3) * 264 + c2] = (unsigned short)(d2.y >> 16);
        h0buf[(qq * 4 + 0) * 264 + c3] = (unsigned short)d3.x;
        h0buf[(qq * 4 + 1) * 264 + c3] = (unsigned short)(d3.x >> 16);
        h0buf[(qq * 4 + 2) * 264 + c3] = (unsigned short)d3.y;
        h0buf[(qq * 4 + 3) * 264 + c3] = (unsigned short)(d3.y >> 16);
        h1buf[(qq * 4 + 0) * 264 + c0] = (unsigned short)e0.x;
        h1buf[(qq * 4 + 1) * 264 + c0] = (unsigned short)(e0.x >> 16);
        h1buf[(qq * 4 + 2) * 264 + c0] = (unsigned short)e0.y;
        h1buf[(qq * 4 + 3) * 264 + c0] = (unsigned short)(e0.y >> 16);
        h1buf[(qq * 4 + 0) * 264 + c1] = (unsigned short)e1.x;
        h1buf[(qq * 4 + 1) * 264 + c1] = (unsigned short)(e1.x >> 16);
        h1buf[(qq * 4 + 2) * 264 + c1] = (unsigned short)e1.y;
        h1buf[(qq * 4 + 3) * 264 + c1] = (unsigned short)(e1.y >> 16);
        h1buf[(qq * 4 + 0) * 264 + c2] = (unsigned short)e2.x;
        h1buf[(qq * 4 + 1) * 264 + c2] = (unsigned short)(e2.x >> 16);
        h1buf[(qq * 4 + 2) * 264 + c2] = (unsigned short)e2.y;
        h1buf[(qq * 4 + 3) * 264 + c2] = (unsigned short)(e2.y >> 16);
        h1buf[(qq * 4 + 0) * 264 + c3] = (unsigned short)e3.x;
        h1buf[(qq * 4 + 1) * 264 + c3] = (unsigned short)(e3.x >> 16);
        h1buf[(qq * 4 + 2) * 264 + c3] = (unsigned short)e3.y;
        h1buf[(qq * 4 + 3) * 264 + c3] = (unsigned short)(e3.y >> 16);
      }
    }
    __syncthreads();  // B3: h0buf=h0_t, h1buf=h1_{t-1}

#pragma unroll
    for (int kt = 0; kt < 4; ++kt) axf[kt] = axn[kt];
  }

  // ---- tail: attention on h1_{511} (last receive) ----
  {
    floatx4 ta = (floatx4){tahbv, tahbv, tahbv, tahbv};
#pragma unroll
    for (int kt = 0; kt < 8; ++kt) {
      const short8 a = *(const short8*)&h1buf[lm * 264 + kt * 32 + q * 8];
      ta = mfma16(a, *(const short8*)&tahWs[fcol * 264 + kt * 32 + q * 8], ta);
    }
#pragma unroll
    for (int r = 0; r < 4; ++r) totB[(q * 4 + r) * 136 + fcol] = f2bf(ta[r]);
    __syncthreads();
    floatx4 sa = (floatx4){tabv, tabv, tabv, tabv};
#pragma unroll
    for (int kt = 0; kt < 4; ++kt) {
      const short8 a = *(const short8*)&totB[lm * 136 + kt * 32 + q * 8];
      sa = mfma16(a, *(const short8*)&taWs[fcol * 136 + kt * 32 + q * 8], sa);
    }
#pragma unroll
    for (int r = 0; r < 4; ++r) {
      const float e = __expf(fmaxf(sa[r], 0.f));
      num[r] += e * ta[r];
      den[r] += e;
    }
  }
  __syncthreads();

  // ---- out[b] = sum_f (num/den)*outW ----
  float* red = &gatebuf[0][0];  // reuse (>= 16*136 floats)
#pragma unroll
  for (int r = 0; r < 4; ++r) red[(q * 4 + r) * 136 + fcol] = (num[r] / den[r]) * outWv;
  __syncthreads();
  if (slice == 0 && tid < 16) {
    float s = 0.f;
    for (int k = 0; k < 128; ++k) s += red[tid * 136 + k];
    out[b0 + tid] = s;
  }
}

// ---------- host ----------
extern "C" void kernel_launch(void* const* d_in, const int* in_sizes, int n_in,
                              void* d_out, int out_size, void* d_ws, size_t ws_size,
                              hipStream_t stream) {
  (void)in_sizes; (void)n_in; (void)out_size; (void)ws_size;
  const float* x    = (const float*)d_in[0];
  const float* bng  = (const float*)d_in[1];
  const float* bnb  = (const float*)d_in[2];
  const float* bnm  = (const float*)d_in[3];
  const float* bnv  = (const float*)d_in[4];
  const float* saW  = (const float*)d_in[5];
  const float* sab  = (const float*)d_in[6];
  const float* inW  = (const float*)d_in[7];
  const float* inb  = (const float*)d_in[8];
  const float* Wih0 = (const float*)d_in[9];
  const float* Whh0 = (const float*)d_in[10];
  const float* bih0 = (const float*)d_in[11];
  const float* bhh0 = (const float*)d_in[12];
  const float* Wih1 = (const float*)d_in[13];
  const float* Whh1 = (const float*)d_in[14];
  const float* bih1 = (const float*)d_in[15];
  const float* bhh1 = (const float*)d_in[16];
  const float* tahW = (const float*)d_in[17];
  const float* tahb = (const float*)d_in[18];
  const float* taW  = (const float*)d_in[19];
  const float* tab  = (const float*)d_in[20];
  const float* outW = (const float*)d_in[21];
  float* out = (float*)d_out;

  char* ws = (char*)d_ws;
  size_t off = 0;
  auto alloc = [&](size_t bytes) {
    char* p = ws + off;
    off += (bytes + 255) & ~(size_t)255;
    return p;
  };
  unsigned short* Wc    = (unsigned short*)alloc((size_t)1024 * 128 * 2);
  float* bc             = (float*)alloc(1024 * 4);
  float* b1             = (float*)alloc(1024 * 4);
  unsigned short* Whh0b = (unsigned short*)alloc((size_t)1024 * 256 * 2);
  unsigned short* Whh1b = (unsigned short*)alloc((size_t)1024 * 256 * 2);
  unsigned short* Wih1b = (unsigned short*)alloc((size_t)1024 * 256 * 2);
  unsigned short* tahWb = (unsigned short*)alloc((size_t)128 * 256 * 2);
  unsigned short* taWb  = (unsigned short*)alloc((size_t)128 * 128 * 2);
  unsigned short* xs    = (unsigned short*)alloc((size_t)131072 * 128 * 2);
  ull2* ex              = (ull2*)alloc((size_t)2 * 16 * 2 * 1024 * 16);  // 1 MB

  hipLaunchKernelGGL(prep_kernel, dim3(921), dim3(256), 0, stream, Wih0, inW, inb, bih0, bhh0,
                     Whh0, Whh1, Wih1, tahW, taW, bih1, bhh1, Wc, bc, Whh0b, Whh1b, Wih1b,
                     tahWb, taWb, b1);
  hipLaunchKernelGGL(bnsa_kernel, dim3(1024), dim3(256), 0, stream, x, bng, bnb, bnm, bnv, saW,
                     sab, xs);
  hipLaunchKernelGGL(persist_kernel, dim3(128), dim3(512), 0, stream, xs, Wc, bc, Whh0b, Wih1b,
                     b1, Whh1b, tahWb, tahb, taWb, tab, outW, ex, out);
}